// Round 6
// baseline (1226.200 us; speedup 1.0000x reference)
//
#include <hip/hip_runtime.h>

#define H 128
#define NODE_DIM 64
#define EDGE_DIM 32
#define KPRE (2*H + EDGE_DIM)   // 288
#define KPOST (13*H)            // 1664
#define T_OUT 256
#define L_DEPTH 5
#define POST_FRAGS (52*8*64)    // fragment-chunks per layer (posttrans W)
#define Y_FRAGS (4*16*64)       // fragment-chunks per layer (ygemm W)
#define WEFT_SZ (H*EDGE_DIM)    // 4096 floats per layer

typedef short short8v __attribute__((ext_vector_type(8)));
typedef float float4v __attribute__((ext_vector_type(4)));

__device__ __forceinline__ unsigned short f2bf(float x) {
    unsigned int b = __float_as_uint(x);
    return (unsigned short)((b + 0x7fffu + ((b >> 16) & 1u)) >> 16);  // RNE
}
__device__ __forceinline__ float bf2f(unsigned short u) {
    return __uint_as_float((unsigned int)u << 16);
}
// scale two packed bf16 by f, repack (RNE via v_cvt_pk_bf16_f32)
__device__ __forceinline__ unsigned int scale2(unsigned int u, float f) {
    float lo = __uint_as_float(u << 16) * f;
    float hi = __uint_as_float(u & 0xffff0000u) * f;
    unsigned int r;
    asm("v_cvt_pk_bf16_f32 %0, %1, %2" : "=v"(r) : "v"(lo), "v"(hi));
    return r;
}

// ---------------- input MLP: h = relu(node_feat @ W_in + b_in) ----------------
__global__ void k_input_mlp(const float* __restrict__ nf, const float* __restrict__ W,
                            const float* __restrict__ b, float* __restrict__ h,
                            unsigned short* __restrict__ h_bf, int N) {
    int gid = blockIdx.x * blockDim.x + threadIdx.x;
    int n = gid >> 7, c = gid & 127;
    if (n >= N) return;
    const float* nrow = nf + (size_t)n * NODE_DIM;
    float acc = 0.f;
#pragma unroll 8
    for (int k = 0; k < NODE_DIM; ++k)
        acc += nrow[k] * W[k * H + c];
    acc += b[c];
    acc = fmaxf(acc, 0.f);
    h[(size_t)n * H + c] = acc;
    h_bf[(size_t)n * H + c] = f2bf(acc);
}

// ---------------- edge sort by dst: histogram, scan, scatter ----------------
__global__ void k_hist(const int* __restrict__ dst, int* __restrict__ deg_i, int E) {
    int e = blockIdx.x * blockDim.x + threadIdx.x;
    if (e < E) atomicAdd(&deg_i[dst[e]], 1);
}

__global__ __launch_bounds__(1024) void k_scan(const int* __restrict__ deg_i,
                                               int* __restrict__ row_start,
                                               int* __restrict__ cursor, int N) {
    __shared__ int part[1024];
    int t = threadIdx.x;
    int per = (N + 1023) / 1024;
    int base = t * per;
    int s = 0;
    for (int i = 0; i < per; ++i) {
        int idx = base + i;
        if (idx < N) s += deg_i[idx];
    }
    part[t] = s;
    __syncthreads();
    for (int off = 1; off < 1024; off <<= 1) {
        int v = (t >= off) ? part[t - off] : 0;
        __syncthreads();
        part[t] += v;
        __syncthreads();
    }
    int run = (t == 0) ? 0 : part[t - 1];
    for (int i = 0; i < per; ++i) {
        int idx = base + i;
        if (idx < N) {
            row_start[idx] = run;
            cursor[idx] = run;
            run += deg_i[idx];
        }
    }
    if (t == 1023) row_start[N] = run;
}

__global__ void k_sortscatter(const int* __restrict__ src, const int* __restrict__ dst,
                              int* __restrict__ cursor, int* __restrict__ es_src,
                              int* __restrict__ es_eid, int E) {
    int e = blockIdx.x * blockDim.x + threadIdx.x;
    if (e >= E) return;
    int pos = atomicAdd(&cursor[dst[e]], 1);
    es_src[pos] = src[e];
    es_eid[pos] = e;
}

// ---- permute edge features into dst-sorted order (once; makes the per-edge
// scalar reads in k_edge_agg sequential instead of random) ----
__global__ void k_efsort(const float* __restrict__ ef, const int* __restrict__ es_eid,
                         float* __restrict__ efs, int E) {
    int t = blockIdx.x * 256 + threadIdx.x;
    int p = t >> 3, q = t & 7;
    if (p >= E) return;
    int eid = es_eid[p];
    *(float4*)&efs[(size_t)p * EDGE_DIM + q * 4] =
        *(const float4*)&ef[(size_t)eid * EDGE_DIM + q * 4];
}

// ---------------- degree scalers ----------------
__global__ void k_scalers(const int* __restrict__ deg_i, float* __restrict__ invd,
                          float* __restrict__ amp, float* __restrict__ att, int N) {
    int n = blockIdx.x * blockDim.x + threadIdx.x;
    if (n >= N) return;
    float d = (float)deg_i[n];
    invd[n] = (d > 0.f) ? (1.f / d) : 0.f;
    float ld = logf(d + 1.f);
    amp[n] = ld;                                 // DELTA == 1.0
    att[n] = (d > 0.f) ? (1.f / ld) : 1.f;
}

// ------- weight conversion, ALL layers at once (weights static per call) -------
__global__ void k_wconv_all(const float* __restrict__ pre_W,
                            const float* __restrict__ post_W,
                            short* __restrict__ wf_y_all,
                            short* __restrict__ wf_post_all,
                            float* __restrict__ wefT_all) {
    int t = blockIdx.x * 256 + threadIdx.x;
    if (t < L_DEPTH * POST_FRAGS) {
        int l = t / POST_FRAGS, tt = t - l * POST_FRAGS;
        const float* qW = post_W + (size_t)l * KPOST * H;
        int lane = tt & 63, fc = tt >> 6;
        int kglob = fc >> 3, cb = fc & 7;
        int col = cb * 16 + (lane & 15);
        int k0 = kglob * 32 + ((lane >> 4) << 3);
        short8v o;
#pragma unroll
        for (int j = 0; j < 8; ++j)
            o[j] = (short)f2bf(qW[(size_t)(k0 + j) * H + col]);
        *(short8v*)(wf_post_all + (size_t)t * 8) = o;
        return;
    }
    t -= L_DEPTH * POST_FRAGS;
    if (t < L_DEPTH * Y_FRAGS) {
        int l = t / Y_FRAGS, tt = t - l * Y_FRAGS;
        const float* pW = pre_W + (size_t)l * KPRE * H;
        int lane = tt & 63, fc = tt >> 6;
        int kglob = fc >> 4, cb = fc & 15;
        int col = cb * 16 + (lane & 15);          // 0..255
        int k0 = kglob * 32 + ((lane >> 4) << 3); // 0..127
        int rowoff = (col < 128) ? 0 : 128;
        int c = col & 127;
        short8v o;
#pragma unroll
        for (int j = 0; j < 8; ++j)
            o[j] = (short)f2bf(pW[(size_t)(rowoff + k0 + j) * H + c]);
        *(short8v*)(wf_y_all + (size_t)t * 8) = o;
        return;
    }
    t -= L_DEPTH * Y_FRAGS;
    if (t >= L_DEPTH * WEFT_SZ) return;
    // WefT[l][c][k] = pre_W[l][(2H+k)*H + c]
    int l = t / WEFT_SZ, i = t - l * WEFT_SZ;
    int c = i >> 5, k = i & 31;
    wefT_all[t] = pre_W[(size_t)l * KPRE * H + (size_t)(2 * H + k) * H + c];
}

// ---------------- Y1(bf16) = h@W_src, Y2(f32) = h@W_dst via MFMA ----------------
__global__ __launch_bounds__(256) void k_ygemm_mfma(
    const unsigned short* __restrict__ h_bf, const short* __restrict__ Wf,
    unsigned short* __restrict__ Y1bf, float* __restrict__ Y2, int N)
{
    __shared__ __align__(16) short Xs[64 * 128];   // 16 KB, XOR-swizzled
    int tid = threadIdx.x;
    int n0 = blockIdx.x * 64;
    int lane = tid & 63, wave = tid >> 6;
    float4v acc[16];
#pragma unroll
    for (int cb = 0; cb < 16; ++cb) acc[cb] = (float4v){0.f, 0.f, 0.f, 0.f};

    int rs = tid >> 4, c0 = (tid & 15) * 8;
#pragma unroll
    for (int j = 0; j < 4; ++j) {
        int r = rs + j * 16;
        int n = n0 + r;
        uint4 v = make_uint4(0, 0, 0, 0);
        if (n < N) v = *(const uint4*)(h_bf + (size_t)n * H + c0);
        *(uint4*)((char*)Xs + r * 256 + ((c0 * 2) ^ ((r & 7) << 4))) = v;
    }
    __syncthreads();
    int rloc = wave * 16 + (lane & 15);
    int swz = (rloc & 7) << 4;
#pragma unroll
    for (int ks = 0; ks < 4; ++ks) {
        int boff = rloc * 256 + (((ks * 64) + ((lane >> 4) << 4)) ^ swz);
        short8v a = *(short8v*)((char*)Xs + boff);
        const short* wp = Wf + ((size_t)(ks * 16) * 64 + lane) * 8;
#pragma unroll
        for (int cb = 0; cb < 16; ++cb) {
            short8v b = *(const short8v*)(wp + (size_t)cb * 512);
            acc[cb] = __builtin_amdgcn_mfma_f32_16x16x32_bf16(a, b, acc[cb], 0, 0, 0);
        }
    }
    int col0 = lane & 15;
    int row0 = wave * 16 + ((lane >> 4) << 2);
#pragma unroll
    for (int cb = 0; cb < 16; ++cb) {
        int col = cb * 16 + col0;
#pragma unroll
        for (int r = 0; r < 4; ++r) {
            int n = n0 + row0 + r;
            if (n < N) {
                if (col < 128) Y1bf[(size_t)n * H + col] = f2bf(acc[cb][r]);
                else           Y2[(size_t)n * H + (col - 128)] = acc[cb][r];
            }
        }
    }
}

// ------- aggregation: per node, reduce relu(Y1[src]+Y2[n]+efs[p]@Wef+pb) -----
// efs is dst-sorted, so the per-edge feature row address depends only on the
// loop counter -> sequential scalar-pipe loads. Outputs stored bf16.
__global__ __launch_bounds__(128) void k_edge_agg(
    const unsigned short* __restrict__ Y1bf, const float* __restrict__ Y2,
    const float* __restrict__ efs, const float* __restrict__ WefT,
    const float* __restrict__ pb,
    const int* __restrict__ es_src, const int* __restrict__ row_start,
    unsigned short* __restrict__ s_out, unsigned short* __restrict__ mx_out,
    unsigned short* __restrict__ mn_out, int N)
{
    int n = blockIdx.x;
    int c = threadIdx.x;   // 0..127 channel
    float4 wr[8];
#pragma unroll
    for (int j = 0; j < 8; ++j)
        wr[j] = *(const float4*)&WefT[c * EDGE_DIM + j * 4];
    int start = row_start[n], end = row_start[n + 1];
    float y2c = Y2[(size_t)n * H + c] + pb[c];
    bool any = end > start;
    float acc_s = 0.f;
    float acc_mx = any ? -3.4e38f : 0.f;
    float acc_mn = any ? 3.4e38f : 0.f;
#pragma unroll 4
    for (int p = start; p < end; ++p) {
        int sn = __builtin_amdgcn_readfirstlane(es_src[p]);
        float y1 = bf2f(Y1bf[(size_t)sn * H + c]);
        const float* efp = efs + (size_t)p * EDGE_DIM;
        float a0 = y1 + y2c, a1 = 0.f, a2 = 0.f, a3 = 0.f;
#pragma unroll
        for (int kk = 0; kk < 8; ++kk) {
            a0 = fmaf(efp[kk],      ((const float*)&wr[kk >> 2])[kk & 3],     a0);
            a1 = fmaf(efp[kk + 8],  ((const float*)&wr[2 + (kk >> 2)])[kk & 3], a1);
            a2 = fmaf(efp[kk + 16], ((const float*)&wr[4 + (kk >> 2)])[kk & 3], a2);
            a3 = fmaf(efp[kk + 24], ((const float*)&wr[6 + (kk >> 2)])[kk & 3], a3);
        }
        float m = fmaxf((a0 + a1) + (a2 + a3), 0.f);
        acc_s += m;
        acc_mx = fmaxf(acc_mx, m);
        acc_mn = fminf(acc_mn, m);
    }
    size_t o = (size_t)n * H + c;
    s_out[o] = f2bf(acc_s);
    mx_out[o] = f2bf(acc_mx);
    mn_out[o] = f2bf(acc_mn);
}

// ---------------- posttrans via MFMA, double-buffered staging ----------------
__global__ __launch_bounds__(128) void k_post_mfma(
    float* __restrict__ h, unsigned short* __restrict__ h_bf,
    const unsigned short* __restrict__ s_in, const unsigned short* __restrict__ mx_in,
    const unsigned short* __restrict__ mn_in,
    const float* __restrict__ invd, const float* __restrict__ amp,
    const float* __restrict__ att,
    const short* __restrict__ Wf, const float* __restrict__ qb, int N)
{
    __shared__ __align__(16) short Xs[2][32 * 128];   // 2 x 8 KB ping-pong
    int tid = threadIdx.x;
    int n0 = blockIdx.x * 32;
    int lane = tid & 63, wave = tid >> 6;
    int rs = tid >> 4, c0 = (tid & 15) * 8;   // 8 rows x 8-ch chunks

    float invd_r[4], amp_r[4], att_r[4];
#pragma unroll
    for (int j = 0; j < 4; ++j) {
        int n = n0 + rs + j * 8;
        bool ok = n < N;
        invd_r[j] = ok ? invd[n] : 0.f;
        amp_r[j]  = ok ? amp[n]  : 0.f;
        att_r[j]  = ok ? att[n]  : 0.f;
    }

    float4v acc[8];
#pragma unroll
    for (int cb = 0; cb < 8; ++cb) acc[cb] = (float4v){0.f, 0.f, 0.f, 0.f};

    uint4 pre[4];
    auto srcptr = [&](int kb) -> const unsigned short* {
        if (kb == 0) return h_bf;
        int comp = (kb - 1) & 3;
        return (comp == 1) ? mx_in : ((comp == 2) ? mn_in : s_in);
    };
    auto issue = [&](int kb) {
        const unsigned short* sp = srcptr(kb);
#pragma unroll
        for (int j = 0; j < 4; ++j) {
            int n = n0 + rs + j * 8;
            pre[j] = (n < N) ? *(const uint4*)(sp + (size_t)n * H + c0)
                             : make_uint4(0, 0, 0, 0);
        }
    };

    issue(0);
#pragma unroll
    for (int kb = 0; kb < 13; ++kb) {
        const int buf = kb & 1;
        // commit: scale + write LDS
        {
            int comp = (kb == 0) ? -1 : ((kb - 1) & 3);
            int grp  = (kb == 0) ? 0  : ((kb - 1) >> 2);
            bool noscale = (kb == 0) || (grp == 0 && comp != 0);
#pragma unroll
            for (int j = 0; j < 4; ++j) {
                int r = rs + j * 8;
                uint4 v = pre[j];
                if (!noscale) {
                    float f = (comp == 0) ? invd_r[j] : 1.f;
                    if (grp == 1)      f *= amp_r[j];
                    else if (grp == 2) f *= att_r[j];
                    v.x = scale2(v.x, f); v.y = scale2(v.y, f);
                    v.z = scale2(v.z, f); v.w = scale2(v.w, f);
                }
                *(uint4*)((char*)&Xs[buf][0] + r * 256 + ((c0 * 2) ^ ((r & 7) << 4))) = v;
            }
        }
        if (kb < 12) issue(kb + 1);   // prefetch next phase across the barrier
        __syncthreads();
        // MFMA on buf
        {
            int rloc = wave * 16 + (lane & 15);   // 0..31
            int swz = (rloc & 7) << 4;
#pragma unroll
            for (int ks = 0; ks < 4; ++ks) {
                int boff = rloc * 256 + (((ks * 64) + ((lane >> 4) << 4)) ^ swz);
                short8v a = *(short8v*)((char*)&Xs[buf][0] + boff);
                const short* wp = Wf + ((size_t)((kb * 4 + ks) * 8) * 64 + lane) * 8;
#pragma unroll
                for (int cb = 0; cb < 8; ++cb) {
                    short8v b = *(const short8v*)(wp + (size_t)cb * 512);
                    acc[cb] = __builtin_amdgcn_mfma_f32_16x16x32_bf16(a, b, acc[cb], 0, 0, 0);
                }
            }
        }
    }
    int col0 = lane & 15;
    int row0 = wave * 16 + ((lane >> 4) << 2);  // 0..31
#pragma unroll
    for (int cb = 0; cb < 8; ++cb) {
        int col = cb * 16 + col0;
        float bb = qb[col];
#pragma unroll
        for (int r = 0; r < 4; ++r) {
            int n = n0 + row0 + r;
            if (n < N) {
                size_t o = (size_t)n * H + col;
                float nv = h[o] + fmaxf(acc[cb][r] + bb, 0.f);
                h[o] = nv;
                h_bf[o] = f2bf(nv);
            }
        }
    }
}

// ---------------- graph readout scatter ----------------
__global__ void k_readout_scatter(const float* __restrict__ h, const int* __restrict__ n2g,
                                  float* __restrict__ g_sum, unsigned int* __restrict__ g_max,
                                  int N) {
    int gid = blockIdx.x * blockDim.x + threadIdx.x;
    int n = gid >> 7, c = gid & 127;
    if (n >= N) return;
    int g = n2g[n];
    float v = h[(size_t)n * H + c];
    atomicAdd(&g_sum[(size_t)g * H + c], v);
    atomicMax(&g_max[(size_t)g * H + c], __float_as_uint(v));  // h >= 0 always
}

__global__ void k_gcnt(const int* __restrict__ n2g, float* __restrict__ g_cnt, int N) {
    int n = blockIdx.x * blockDim.x + threadIdx.x;
    if (n < N) atomicAdd(&g_cnt[n2g[n]], 1.f);
}

// ---------------- final MLP ----------------
__global__ __launch_bounds__(256) void k_final(
    const float* __restrict__ g_sum, const float* __restrict__ g_max,
    const float* __restrict__ g_cnt,
    const float* __restrict__ W1, const float* __restrict__ b1,
    const float* __restrict__ W2, const float* __restrict__ b2,
    float* __restrict__ out)
{
    __shared__ float hid[H];
    int b = blockIdx.x, t = threadIdx.x;
    float cnt = g_cnt[b];
    if (t < H) {
        float acc = 0.f;
        float rc = 1.f / fmaxf(cnt, 1.f);
        for (int k = 0; k < 3 * H; ++k) {
            float x;
            if (k < H)          x = g_sum[(size_t)b * H + k] * rc;
            else if (k < 2 * H) x = (cnt > 0.f) ? g_max[(size_t)b * H + (k - H)] : 0.f;
            else                x = g_sum[(size_t)b * H + (k - 2 * H)];
            acc += x * W1[k * H + t];
        }
        hid[t] = fmaxf(acc + b1[t], 0.f);
    }
    __syncthreads();
    float acc = 0.f;
#pragma unroll 8
    for (int k = 0; k < H; ++k)
        acc += hid[k] * W2[k * T_OUT + t];
    out[(size_t)b * T_OUT + t] = acc + b2[t];
}

extern "C" void kernel_launch(void* const* d_in, const int* in_sizes, int n_in,
                              void* d_out, int out_size, void* d_ws, size_t ws_size,
                              hipStream_t stream) {
    const float* node_feat = (const float*)d_in[0];
    const float* edge_feat = (const float*)d_in[1];
    const float* W_in  = (const float*)d_in[2];
    const float* b_in  = (const float*)d_in[3];
    const float* pre_W = (const float*)d_in[4];
    const float* pre_b = (const float*)d_in[5];
    const float* post_W = (const float*)d_in[6];
    const float* post_b = (const float*)d_in[7];
    const float* out_W1 = (const float*)d_in[8];
    const float* out_b1 = (const float*)d_in[9];
    const float* out_W2 = (const float*)d_in[10];
    const float* out_b2 = (const float*)d_in[11];
    const int* src = (const int*)d_in[12];
    const int* dst = (const int*)d_in[13];
    const int* n2g = (const int*)d_in[14];

    int N = in_sizes[0] / NODE_DIM;
    int E = in_sizes[1] / EDGE_DIM;
    int B = out_size / T_OUT;
    float* out = (float*)d_out;

    float* ws = (float*)d_ws;
    float* h      = ws; ws += (size_t)N * H;
    float* Y2     = ws; ws += (size_t)N * H;
    float* invd = ws; ws += N;
    float* amp  = ws; ws += N;
    float* att  = ws; ws += N;
    float* g_sum = ws; ws += (size_t)B * H;
    unsigned int* g_max = (unsigned int*)ws; ws += (size_t)B * H;
    float* g_cnt = ws; ws += B;
    // pad to 16B boundary for the float4/uint4 arrays below
    ws = (float*)(((uintptr_t)ws + 15) & ~(uintptr_t)15);
    float* efs      = ws; ws += (size_t)E * EDGE_DIM;
    float* wefT_all = ws; ws += (size_t)L_DEPTH * WEFT_SZ;
    unsigned short* h_bf  = (unsigned short*)ws;
    unsigned short* s_buf = h_bf  + (size_t)N * H;
    unsigned short* mx    = s_buf + (size_t)N * H;
    unsigned short* mn    = mx    + (size_t)N * H;
    unsigned short* Y1bf  = mn    + (size_t)N * H;
    short* wf_post_all = (short*)(Y1bf + (size_t)N * H);
    short* wf_y_all    = wf_post_all + (size_t)L_DEPTH * POST_FRAGS * 8;
    int* deg_i     = (int*)(wf_y_all + (size_t)L_DEPTH * Y_FRAGS * 8);
    int* row_start = deg_i + N;
    int* cursor    = row_start + N + 1;
    int* es_src    = cursor + N;
    int* es_eid    = es_src + E;

    // input MLP (h fp32 + bf16 shadow)
    k_input_mlp<<<((size_t)N * H + 255) / 256, 256, 0, stream>>>(node_feat, W_in, b_in,
                                                                 h, h_bf, N);

    // edge sort by dst (dst static across layers)
    hipMemsetAsync(deg_i, 0, (size_t)N * sizeof(int), stream);
    k_hist<<<(E + 255) / 256, 256, 0, stream>>>(dst, deg_i, E);
    k_scan<<<1, 1024, 0, stream>>>(deg_i, row_start, cursor, N);
    k_sortscatter<<<(E + 255) / 256, 256, 0, stream>>>(src, dst, cursor, es_src, es_eid, E);
    k_efsort<<<((size_t)E * 8 + 255) / 256, 256, 0, stream>>>(edge_feat, es_eid, efs, E);
    k_scalers<<<(N + 255) / 256, 256, 0, stream>>>(deg_i, invd, amp, att, N);

    // all-layer weight conversion (once)
    {
        int tot = L_DEPTH * (POST_FRAGS + Y_FRAGS + WEFT_SZ);
        k_wconv_all<<<(tot + 255) / 256, 256, 0, stream>>>(pre_W, post_W, wf_y_all,
                                                           wf_post_all, wefT_all);
    }

    for (int l = 0; l < L_DEPTH; ++l) {
        k_ygemm_mfma<<<(N + 63) / 64, 256, 0, stream>>>(
            h_bf, wf_y_all + (size_t)l * Y_FRAGS * 8, Y1bf, Y2, N);
        k_edge_agg<<<N, 128, 0, stream>>>(
            Y1bf, Y2, efs, wefT_all + (size_t)l * WEFT_SZ, pre_b + (size_t)l * H,
            es_src, row_start, s_buf, mx, mn, N);
        k_post_mfma<<<(N + 31) / 32, 128, 0, stream>>>(
            h, h_bf, s_buf, mx, mn, invd, amp, att,
            wf_post_all + (size_t)l * POST_FRAGS * 8, post_b + (size_t)l * H, N);
    }

    // readout
    hipMemsetAsync(g_sum, 0, (size_t)B * H * sizeof(float), stream);
    hipMemsetAsync(g_max, 0, (size_t)B * H * sizeof(float), stream);
    hipMemsetAsync(g_cnt, 0, (size_t)B * sizeof(float), stream);
    k_readout_scatter<<<((size_t)N * H + 255) / 256, 256, 0, stream>>>(h, n2g, g_sum, g_max, N);
    k_gcnt<<<(N + 255) / 256, 256, 0, stream>>>(n2g, g_cnt, N);
    k_final<<<B, 256, 0, stream>>>(g_sum, (const float*)g_max, g_cnt,
                                   out_W1, out_b1, out_W2, out_b2, out);
}

// Round 7
// 984.814 us; speedup vs baseline: 1.2451x; 1.2451x over previous
//
#include <hip/hip_runtime.h>

#define H 128
#define NODE_DIM 64
#define EDGE_DIM 32
#define KPRE (2*H + EDGE_DIM)   // 288
#define KPOST (13*H)            // 1664
#define T_OUT 256
#define L_DEPTH 5
#define POST_FRAGS (52*8*64)    // fragment-chunks per layer (posttrans W)
#define Y_FRAGS (4*16*64)       // fragment-chunks per layer (ygemm W)
#define WEFT_SZ (H*EDGE_DIM)    // 4096 floats per layer

typedef short short8v __attribute__((ext_vector_type(8)));
typedef float float4v __attribute__((ext_vector_type(4)));

__device__ __forceinline__ unsigned short f2bf(float x) {
    unsigned int b = __float_as_uint(x);
    return (unsigned short)((b + 0x7fffu + ((b >> 16) & 1u)) >> 16);  // RNE
}
__device__ __forceinline__ float bf2f(unsigned short u) {
    return __uint_as_float((unsigned int)u << 16);
}
// scale two packed bf16 by f, repack in plain C (no inline asm — m240)
__device__ __forceinline__ unsigned int scale2c(unsigned int u, float f) {
    float lo = __uint_as_float(u << 16) * f;
    float hi = __uint_as_float(u & 0xffff0000u) * f;
    return (unsigned int)f2bf(lo) | ((unsigned int)f2bf(hi) << 16);
}

// ---------------- input MLP: h = relu(node_feat @ W_in + b_in) ----------------
__global__ void k_input_mlp(const float* __restrict__ nf, const float* __restrict__ W,
                            const float* __restrict__ b, float* __restrict__ h,
                            unsigned short* __restrict__ h_bf, int N) {
    int gid = blockIdx.x * blockDim.x + threadIdx.x;
    int n = gid >> 7, c = gid & 127;
    if (n >= N) return;
    const float* nrow = nf + (size_t)n * NODE_DIM;
    float acc = 0.f;
#pragma unroll 8
    for (int k = 0; k < NODE_DIM; ++k)
        acc += nrow[k] * W[k * H + c];
    acc += b[c];
    acc = fmaxf(acc, 0.f);
    h[(size_t)n * H + c] = acc;
    h_bf[(size_t)n * H + c] = f2bf(acc);
}

// ---------------- edge sort by dst: histogram, scan, scatter ----------------
__global__ void k_hist(const int* __restrict__ dst, int* __restrict__ deg_i, int E) {
    int e = blockIdx.x * blockDim.x + threadIdx.x;
    if (e < E) atomicAdd(&deg_i[dst[e]], 1);
}

__global__ __launch_bounds__(1024) void k_scan(const int* __restrict__ deg_i,
                                               int* __restrict__ row_start,
                                               int* __restrict__ cursor, int N) {
    __shared__ int part[1024];
    int t = threadIdx.x;
    int per = (N + 1023) / 1024;
    int base = t * per;
    int s = 0;
    for (int i = 0; i < per; ++i) {
        int idx = base + i;
        if (idx < N) s += deg_i[idx];
    }
    part[t] = s;
    __syncthreads();
    for (int off = 1; off < 1024; off <<= 1) {
        int v = (t >= off) ? part[t - off] : 0;
        __syncthreads();
        part[t] += v;
        __syncthreads();
    }
    int run = (t == 0) ? 0 : part[t - 1];
    for (int i = 0; i < per; ++i) {
        int idx = base + i;
        if (idx < N) {
            row_start[idx] = run;
            cursor[idx] = run;
            run += deg_i[idx];
        }
    }
    if (t == 1023) row_start[N] = run;
}

__global__ void k_sortscatter(const int* __restrict__ src, const int* __restrict__ dst,
                              int* __restrict__ cursor, int* __restrict__ es_src,
                              int* __restrict__ es_eid, int E) {
    int e = blockIdx.x * blockDim.x + threadIdx.x;
    if (e >= E) return;
    int pos = atomicAdd(&cursor[dst[e]], 1);
    es_src[pos] = src[e];
    es_eid[pos] = e;
}

// ---- permute edge features into dst-sorted order (once) ----
__global__ void k_efsort(const float* __restrict__ ef, const int* __restrict__ es_eid,
                         float* __restrict__ efs, int E) {
    int t = blockIdx.x * 256 + threadIdx.x;
    int p = t >> 3, q = t & 7;
    if (p >= E) return;
    int eid = es_eid[p];
    *(float4*)&efs[(size_t)p * EDGE_DIM + q * 4] =
        *(const float4*)&ef[(size_t)eid * EDGE_DIM + q * 4];
}

// ---------------- degree scalers ----------------
__global__ void k_scalers(const int* __restrict__ deg_i, float* __restrict__ invd,
                          float* __restrict__ amp, float* __restrict__ att, int N) {
    int n = blockIdx.x * blockDim.x + threadIdx.x;
    if (n >= N) return;
    float d = (float)deg_i[n];
    invd[n] = (d > 0.f) ? (1.f / d) : 0.f;
    float ld = logf(d + 1.f);
    amp[n] = ld;                                 // DELTA == 1.0
    att[n] = (d > 0.f) ? (1.f / ld) : 1.f;
}

// ------- weight conversion, ALL layers at once (weights static per call) -------
__global__ void k_wconv_all(const float* __restrict__ pre_W,
                            const float* __restrict__ post_W,
                            short* __restrict__ wf_y_all,
                            short* __restrict__ wf_post_all,
                            float* __restrict__ wefT_all) {
    int t = blockIdx.x * 256 + threadIdx.x;
    if (t < L_DEPTH * POST_FRAGS) {
        int l = t / POST_FRAGS, tt = t - l * POST_FRAGS;
        const float* qW = post_W + (size_t)l * KPOST * H;
        int lane = tt & 63, fc = tt >> 6;
        int kglob = fc >> 3, cb = fc & 7;
        int col = cb * 16 + (lane & 15);
        int k0 = kglob * 32 + ((lane >> 4) << 3);
        short8v o;
#pragma unroll
        for (int j = 0; j < 8; ++j)
            o[j] = (short)f2bf(qW[(size_t)(k0 + j) * H + col]);
        *(short8v*)(wf_post_all + (size_t)t * 8) = o;
        return;
    }
    t -= L_DEPTH * POST_FRAGS;
    if (t < L_DEPTH * Y_FRAGS) {
        int l = t / Y_FRAGS, tt = t - l * Y_FRAGS;
        const float* pW = pre_W + (size_t)l * KPRE * H;
        int lane = tt & 63, fc = tt >> 6;
        int kglob = fc >> 4, cb = fc & 15;
        int col = cb * 16 + (lane & 15);          // 0..255
        int k0 = kglob * 32 + ((lane >> 4) << 3); // 0..127
        int rowoff = (col < 128) ? 0 : 128;
        int c = col & 127;
        short8v o;
#pragma unroll
        for (int j = 0; j < 8; ++j)
            o[j] = (short)f2bf(pW[(size_t)(rowoff + k0 + j) * H + c]);
        *(short8v*)(wf_y_all + (size_t)t * 8) = o;
        return;
    }
    t -= L_DEPTH * Y_FRAGS;
    if (t >= L_DEPTH * WEFT_SZ) return;
    int l = t / WEFT_SZ, i = t - l * WEFT_SZ;
    int c = i >> 5, k = i & 31;
    wefT_all[t] = pre_W[(size_t)l * KPRE * H + (size_t)(2 * H + k) * H + c];
}

// ---------------- Y1(bf16) = h@W_src, Y2(f32) = h@W_dst via MFMA (layer 0 only) --
__global__ __launch_bounds__(256) void k_ygemm_mfma(
    const unsigned short* __restrict__ h_bf, const short* __restrict__ Wf,
    unsigned short* __restrict__ Y1bf, float* __restrict__ Y2, int N)
{
    __shared__ __align__(16) short Xs[64 * 128];   // 16 KB, XOR-swizzled
    int tid = threadIdx.x;
    int n0 = blockIdx.x * 64;
    int lane = tid & 63, wave = tid >> 6;
    float4v acc[16];
#pragma unroll
    for (int cb = 0; cb < 16; ++cb) acc[cb] = (float4v){0.f, 0.f, 0.f, 0.f};

    int rs = tid >> 4, c0 = (tid & 15) * 8;
#pragma unroll
    for (int j = 0; j < 4; ++j) {
        int r = rs + j * 16;
        int n = n0 + r;
        uint4 v = make_uint4(0, 0, 0, 0);
        if (n < N) v = *(const uint4*)(h_bf + (size_t)n * H + c0);
        *(uint4*)((char*)Xs + r * 256 + ((c0 * 2) ^ ((r & 7) << 4))) = v;
    }
    __syncthreads();
    int rloc = wave * 16 + (lane & 15);
    int swz = (rloc & 7) << 4;
#pragma unroll
    for (int ks = 0; ks < 4; ++ks) {
        int boff = rloc * 256 + (((ks * 64) + ((lane >> 4) << 4)) ^ swz);
        short8v a = *(short8v*)((char*)Xs + boff);
        const short* wp = Wf + ((size_t)(ks * 16) * 64 + lane) * 8;
#pragma unroll
        for (int cb = 0; cb < 16; ++cb) {
            short8v b = *(const short8v*)(wp + (size_t)cb * 512);
            acc[cb] = __builtin_amdgcn_mfma_f32_16x16x32_bf16(a, b, acc[cb], 0, 0, 0);
        }
    }
    int col0 = lane & 15;
    int row0 = wave * 16 + ((lane >> 4) << 2);
#pragma unroll
    for (int cb = 0; cb < 16; ++cb) {
        int col = cb * 16 + col0;
#pragma unroll
        for (int r = 0; r < 4; ++r) {
            int n = n0 + row0 + r;
            if (n < N) {
                if (col < 128) Y1bf[(size_t)n * H + col] = f2bf(acc[cb][r]);
                else           Y2[(size_t)n * H + (col - 128)] = acc[cb][r];
            }
        }
    }
}

// ------- aggregation: per node, reduce relu(Y1[src]+Y2[n]+efs[p]@Wef+pb) -----
__global__ __launch_bounds__(128) void k_edge_agg(
    const unsigned short* __restrict__ Y1bf, const float* __restrict__ Y2,
    const float* __restrict__ efs, const float* __restrict__ WefT,
    const float* __restrict__ pb,
    const int* __restrict__ es_src, const int* __restrict__ row_start,
    unsigned short* __restrict__ s_out, unsigned short* __restrict__ mx_out,
    unsigned short* __restrict__ mn_out, int N)
{
    int n = blockIdx.x;
    int c = threadIdx.x;   // 0..127 channel
    float4 wr[8];
#pragma unroll
    for (int j = 0; j < 8; ++j)
        wr[j] = *(const float4*)&WefT[c * EDGE_DIM + j * 4];
    int start = row_start[n], end = row_start[n + 1];
    float y2c = Y2[(size_t)n * H + c] + pb[c];
    bool any = end > start;
    float acc_s = 0.f;
    float acc_mx = any ? -3.4e38f : 0.f;
    float acc_mn = any ? 3.4e38f : 0.f;
#pragma unroll 4
    for (int p = start; p < end; ++p) {
        int sn = __builtin_amdgcn_readfirstlane(es_src[p]);
        float y1 = bf2f(Y1bf[(size_t)sn * H + c]);
        const float* efp = efs + (size_t)p * EDGE_DIM;
        float a0 = y1 + y2c, a1 = 0.f, a2 = 0.f, a3 = 0.f;
#pragma unroll
        for (int kk = 0; kk < 8; ++kk) {
            a0 = fmaf(efp[kk],      ((const float*)&wr[kk >> 2])[kk & 3],     a0);
            a1 = fmaf(efp[kk + 8],  ((const float*)&wr[2 + (kk >> 2)])[kk & 3], a1);
            a2 = fmaf(efp[kk + 16], ((const float*)&wr[4 + (kk >> 2)])[kk & 3], a2);
            a3 = fmaf(efp[kk + 24], ((const float*)&wr[6 + (kk >> 2)])[kk & 3], a3);
        }
        float m = fmaxf((a0 + a1) + (a2 + a3), 0.f);
        acc_s += m;
        acc_mx = fmaxf(acc_mx, m);
        acc_mn = fminf(acc_mn, m);
    }
    size_t o = (size_t)n * H + c;
    s_out[o] = f2bf(acc_s);
    mx_out[o] = f2bf(acc_mx);
    mn_out[o] = f2bf(acc_mn);
}

// ------- posttrans via MFMA (4 waves) + fused next-layer ygemm ---------------
// waves: rh = wave&1 (row half of 32), ch = wave>>1 (col half of 128).
__global__ __launch_bounds__(256) void k_post_mfma(
    float* __restrict__ h, unsigned short* __restrict__ h_bf,
    const unsigned short* __restrict__ s_in, const unsigned short* __restrict__ mx_in,
    const unsigned short* __restrict__ mn_in,
    const float* __restrict__ invd, const float* __restrict__ amp,
    const float* __restrict__ att,
    const short* __restrict__ Wf, const float* __restrict__ qb,
    const short* __restrict__ WfY, unsigned short* __restrict__ Y1bf,
    float* __restrict__ Y2, int doY, int N)
{
    __shared__ __align__(16) short Xs[2][32 * 128];   // 2 x 8 KB ping-pong
    int tid = threadIdx.x;
    int n0 = blockIdx.x * 32;
    int lane = tid & 63, wave = tid >> 6;
    int rh = wave & 1, ch = wave >> 1;
    int rs = tid >> 4, c0 = (tid & 15) * 8;   // staging: 16 rows x 16 chunks, x2

    float invd_r[2], amp_r[2], att_r[2];
#pragma unroll
    for (int j = 0; j < 2; ++j) {
        int n = n0 + rs + j * 16;
        bool ok = n < N;
        invd_r[j] = ok ? invd[n] : 0.f;
        amp_r[j]  = ok ? amp[n]  : 0.f;
        att_r[j]  = ok ? att[n]  : 0.f;
    }

    float4v acc[4];
#pragma unroll
    for (int cb = 0; cb < 4; ++cb) acc[cb] = (float4v){0.f, 0.f, 0.f, 0.f};

    uint4 preA[2], preB[2];   // depth-2 prefetch, static slots (rule #20)
    auto srcptr = [&](int kb) -> const unsigned short* {
        if (kb == 0) return h_bf;
        int comp = (kb - 1) & 3;
        return (comp == 1) ? mx_in : ((comp == 2) ? mn_in : s_in);
    };
    auto issue = [&](int kb, uint4* dst) {
        const unsigned short* sp = srcptr(kb);
#pragma unroll
        for (int j = 0; j < 2; ++j) {
            int n = n0 + rs + j * 16;
            dst[j] = (n < N) ? *(const uint4*)(sp + (size_t)n * H + c0)
                             : make_uint4(0, 0, 0, 0);
        }
    };
    auto commit = [&](int kb, const uint4* src, int buf) {
        int comp = (kb == 0) ? -1 : ((kb - 1) & 3);
        int grp  = (kb == 0) ? 0  : ((kb - 1) >> 2);
        bool noscale = (kb == 0) || (grp == 0 && comp != 0);
#pragma unroll
        for (int j = 0; j < 2; ++j) {
            int r = rs + j * 16;
            uint4 v = src[j];
            if (!noscale) {
                float f = (comp == 0) ? invd_r[j] : 1.f;
                if (grp == 1)      f *= amp_r[j];
                else if (grp == 2) f *= att_r[j];
                v.x = scale2c(v.x, f); v.y = scale2c(v.y, f);
                v.z = scale2c(v.z, f); v.w = scale2c(v.w, f);
            }
            *(uint4*)((char*)&Xs[buf][0] + r * 256 + ((c0 * 2) ^ ((r & 7) << 4))) = v;
        }
    };

    issue(0, preA);
    issue(1, preB);
#pragma unroll
    for (int kb = 0; kb < 13; ++kb) {
        const int buf = kb & 1;
        if (kb & 1) { commit(kb, preB, buf); if (kb + 2 < 13) issue(kb + 2, preB); }
        else        { commit(kb, preA, buf); if (kb + 2 < 13) issue(kb + 2, preA); }
        __syncthreads();
        int rloc = rh * 16 + (lane & 15);
        int swz = (rloc & 7) << 4;
#pragma unroll
        for (int ks = 0; ks < 4; ++ks) {
            int boff = rloc * 256 + (((ks * 64) + ((lane >> 4) << 4)) ^ swz);
            short8v a = *(short8v*)((char*)&Xs[buf][0] + boff);
#pragma unroll
            for (int cb = 0; cb < 4; ++cb) {
                const short* wp = Wf + ((size_t)((kb * 4 + ks) * 8 + ch * 4 + cb) * 64 + lane) * 8;
                short8v b = *(const short8v*)wp;
                acc[cb] = __builtin_amdgcn_mfma_f32_16x16x32_bf16(a, b, acc[cb], 0, 0, 0);
            }
        }
    }
    __syncthreads();   // all reads of Xs[0] (kb=12) done before reuse below
    int col0 = lane & 15;
    int row0 = rh * 16 + ((lane >> 4) << 2);
#pragma unroll
    for (int cb = 0; cb < 4; ++cb) {
        int col = (ch * 4 + cb) * 16 + col0;
        float bb = qb[col];
#pragma unroll
        for (int r = 0; r < 4; ++r) {
            int n = n0 + row0 + r;
            if (n < N) {
                size_t o = (size_t)n * H + col;
                float nv = h[o] + fmaxf(acc[cb][r] + bb, 0.f);
                h[o] = nv;
                unsigned short us = f2bf(nv);
                h_bf[o] = us;
                if (doY) {
                    int rr = row0 + r;
                    *(short*)((char*)&Xs[0][0] + rr * 256 + ((col * 2) ^ ((rr & 7) << 4))) =
                        (short)us;
                }
            }
        }
    }
    if (doY) {
        __syncthreads();
        // Y-GEMM: [32 x 128] @ [128 x 256]; wave handles cols wave*64..+63
        float4v yacc[8];
#pragma unroll
        for (int i = 0; i < 8; ++i) yacc[i] = (float4v){0.f, 0.f, 0.f, 0.f};
#pragma unroll
        for (int t16 = 0; t16 < 2; ++t16) {
            int rloc = t16 * 16 + (lane & 15);
            int swz = (rloc & 7) << 4;
#pragma unroll
            for (int ks = 0; ks < 4; ++ks) {
                int boff = rloc * 256 + (((ks * 64) + ((lane >> 4) << 4)) ^ swz);
                short8v a = *(short8v*)((char*)&Xs[0][0] + boff);
#pragma unroll
                for (int cb = 0; cb < 4; ++cb) {
                    const short* wp = WfY + ((size_t)(ks * 16 + wave * 4 + cb) * 64 + lane) * 8;
                    short8v b = *(const short8v*)wp;
                    yacc[t16 * 4 + cb] =
                        __builtin_amdgcn_mfma_f32_16x16x32_bf16(a, b, yacc[t16 * 4 + cb], 0, 0, 0);
                }
            }
        }
#pragma unroll
        for (int t16 = 0; t16 < 2; ++t16) {
#pragma unroll
            for (int cb = 0; cb < 4; ++cb) {
                int col = (wave * 4 + cb) * 16 + col0;
                int r0 = t16 * 16 + ((lane >> 4) << 2);
#pragma unroll
                for (int r = 0; r < 4; ++r) {
                    int n = n0 + r0 + r;
                    if (n < N) {
                        float v = yacc[t16 * 4 + cb][r];
                        if (col < 128) Y1bf[(size_t)n * H + col] = f2bf(v);
                        else           Y2[(size_t)n * H + (col - 128)] = v;
                    }
                }
            }
        }
    }
}

// ---------------- graph readout scatter ----------------
__global__ void k_readout_scatter(const float* __restrict__ h, const int* __restrict__ n2g,
                                  float* __restrict__ g_sum, unsigned int* __restrict__ g_max,
                                  int N) {
    int gid = blockIdx.x * blockDim.x + threadIdx.x;
    int n = gid >> 7, c = gid & 127;
    if (n >= N) return;
    int g = n2g[n];
    float v = h[(size_t)n * H + c];
    atomicAdd(&g_sum[(size_t)g * H + c], v);
    atomicMax(&g_max[(size_t)g * H + c], __float_as_uint(v));  // h >= 0 always
}

__global__ void k_gcnt(const int* __restrict__ n2g, float* __restrict__ g_cnt, int N) {
    int n = blockIdx.x * blockDim.x + threadIdx.x;
    if (n < N) atomicAdd(&g_cnt[n2g[n]], 1.f);
}

// ---------------- final MLP ----------------
__global__ __launch_bounds__(256) void k_final(
    const float* __restrict__ g_sum, const float* __restrict__ g_max,
    const float* __restrict__ g_cnt,
    const float* __restrict__ W1, const float* __restrict__ b1,
    const float* __restrict__ W2, const float* __restrict__ b2,
    float* __restrict__ out)
{
    __shared__ float hid[H];
    int b = blockIdx.x, t = threadIdx.x;
    float cnt = g_cnt[b];
    if (t < H) {
        float acc = 0.f;
        float rc = 1.f / fmaxf(cnt, 1.f);
        for (int k = 0; k < 3 * H; ++k) {
            float x;
            if (k < H)          x = g_sum[(size_t)b * H + k] * rc;
            else if (k < 2 * H) x = (cnt > 0.f) ? g_max[(size_t)b * H + (k - H)] : 0.f;
            else                x = g_sum[(size_t)b * H + (k - 2 * H)];
            acc += x * W1[k * H + t];
        }
        hid[t] = fmaxf(acc + b1[t], 0.f);
    }
    __syncthreads();
    float acc = 0.f;
#pragma unroll 8
    for (int k = 0; k < H; ++k)
        acc += hid[k] * W2[k * T_OUT + t];
    out[(size_t)b * T_OUT + t] = acc + b2[t];
}

extern "C" void kernel_launch(void* const* d_in, const int* in_sizes, int n_in,
                              void* d_out, int out_size, void* d_ws, size_t ws_size,
                              hipStream_t stream) {
    const float* node_feat = (const float*)d_in[0];
    const float* edge_feat = (const float*)d_in[1];
    const float* W_in  = (const float*)d_in[2];
    const float* b_in  = (const float*)d_in[3];
    const float* pre_W = (const float*)d_in[4];
    const float* pre_b = (const float*)d_in[5];
    const float* post_W = (const float*)d_in[6];
    const float* post_b = (const float*)d_in[7];
    const float* out_W1 = (const float*)d_in[8];
    const float* out_b1 = (const float*)d_in[9];
    const float* out_W2 = (const float*)d_in[10];
    const float* out_b2 = (const float*)d_in[11];
    const int* src = (const int*)d_in[12];
    const int* dst = (const int*)d_in[13];
    const int* n2g = (const int*)d_in[14];

    int N = in_sizes[0] / NODE_DIM;
    int E = in_sizes[1] / EDGE_DIM;
    int B = out_size / T_OUT;
    float* out = (float*)d_out;

    float* ws = (float*)d_ws;
    float* h      = ws; ws += (size_t)N * H;
    float* Y2     = ws; ws += (size_t)N * H;
    float* invd = ws; ws += N;
    float* amp  = ws; ws += N;
    float* att  = ws; ws += N;
    float* g_sum = ws; ws += (size_t)B * H;
    unsigned int* g_max = (unsigned int*)ws; ws += (size_t)B * H;
    float* g_cnt = ws; ws += B;
    ws = (float*)(((uintptr_t)ws + 15) & ~(uintptr_t)15);
    float* efs      = ws; ws += (size_t)E * EDGE_DIM;
    float* wefT_all = ws; ws += (size_t)L_DEPTH * WEFT_SZ;
    unsigned short* h_bf  = (unsigned short*)ws;
    unsigned short* s_buf = h_bf  + (size_t)N * H;
    unsigned short* mx    = s_buf + (size_t)N * H;
    unsigned short* mn    = mx    + (size_t)N * H;
    unsigned short* Y1bf  = mn    + (size_t)N * H;
    short* wf_post_all = (short*)(Y1bf + (size_t)N * H);
    short* wf_y_all    = wf_post_all + (size_t)L_DEPTH * POST_FRAGS * 8;
    int* deg_i     = (int*)(wf_y_all + (size_t)L_DEPTH * Y_FRAGS * 8);
    int* row_start = deg_i + N;
    int* cursor    = row_start + N + 1;
    int* es_src    = cursor + N;
    int* es_eid    = es_src + E;

    // input MLP (h fp32 + bf16 shadow)
    k_input_mlp<<<((size_t)N * H + 255) / 256, 256, 0, stream>>>(node_feat, W_in, b_in,
                                                                 h, h_bf, N);

    // edge sort by dst (dst static across layers)
    hipMemsetAsync(deg_i, 0, (size_t)N * sizeof(int), stream);
    k_hist<<<(E + 255) / 256, 256, 0, stream>>>(dst, deg_i, E);
    k_scan<<<1, 1024, 0, stream>>>(deg_i, row_start, cursor, N);
    k_sortscatter<<<(E + 255) / 256, 256, 0, stream>>>(src, dst, cursor, es_src, es_eid, E);
    k_efsort<<<((size_t)E * 8 + 255) / 256, 256, 0, stream>>>(edge_feat, es_eid, efs, E);
    k_scalers<<<(N + 255) / 256, 256, 0, stream>>>(deg_i, invd, amp, att, N);

    // all-layer weight conversion (once)
    {
        int tot = L_DEPTH * (POST_FRAGS + Y_FRAGS + WEFT_SZ);
        k_wconv_all<<<(tot + 255) / 256, 256, 0, stream>>>(pre_W, post_W, wf_y_all,
                                                           wf_post_all, wefT_all);
    }

    for (int l = 0; l < L_DEPTH; ++l) {
        if (l == 0)
            k_ygemm_mfma<<<(N + 63) / 64, 256, 0, stream>>>(
                h_bf, wf_y_all, Y1bf, Y2, N);
        k_edge_agg<<<N, 128, 0, stream>>>(
            Y1bf, Y2, efs, wefT_all + (size_t)l * WEFT_SZ, pre_b + (size_t)l * H,
            es_src, row_start, s_buf, mx, mn, N);
        int doY = (l < L_DEPTH - 1) ? 1 : 0;
        k_post_mfma<<<(N + 31) / 32, 256, 0, stream>>>(
            h, h_bf, s_buf, mx, mn, invd, amp, att,
            wf_post_all + (size_t)l * POST_FRAGS * 8, post_b + (size_t)l * H,
            doY ? (wf_y_all + (size_t)(l + 1) * Y_FRAGS * 8) : wf_y_all,
            Y1bf, Y2, doY, N);
    }

    // readout
    hipMemsetAsync(g_sum, 0, (size_t)B * H * sizeof(float), stream);
    hipMemsetAsync(g_max, 0, (size_t)B * H * sizeof(float), stream);
    hipMemsetAsync(g_cnt, 0, (size_t)B * sizeof(float), stream);
    k_readout_scatter<<<((size_t)N * H + 255) / 256, 256, 0, stream>>>(h, n2g, g_sum, g_max, N);
    k_gcnt<<<(N + 255) / 256, 256, 0, stream>>>(n2g, g_cnt, N);
    k_final<<<B, 256, 0, stream>>>(g_sum, (const float*)g_max, g_cnt,
                                   out_W1, out_b1, out_W2, out_b2, out);
}

// Round 8
// 861.719 us; speedup vs baseline: 1.4230x; 1.1428x over previous
//
#include <hip/hip_runtime.h>

#define H 128
#define NODE_DIM 64
#define EDGE_DIM 32
#define KPRE (2*H + EDGE_DIM)   // 288
#define KPOST (13*H)            // 1664
#define T_OUT 256
#define L_DEPTH 5
#define POST_FRAGS (52*8*64)    // fragment-chunks per layer (posttrans W, permuted order)
#define Y_FRAGS (4*16*64)       // fragment-chunks per layer (ygemm W)
#define EF_FRAGS (8*64)         // fragment-chunks per layer (ef W)

typedef short short8v __attribute__((ext_vector_type(8)));
typedef float float4v __attribute__((ext_vector_type(4)));

__device__ __forceinline__ unsigned short f2bf(float x) {
    unsigned int b = __float_as_uint(x);
    return (unsigned short)((b + 0x7fffu + ((b >> 16) & 1u)) >> 16);  // RNE
}
__device__ __forceinline__ float bf2f(unsigned short u) {
    return __uint_as_float((unsigned int)u << 16);
}

// ---------------- input MLP: h = relu(node_feat @ W_in + b_in) ----------------
__global__ void k_input_mlp(const float* __restrict__ nf, const float* __restrict__ W,
                            const float* __restrict__ b, float* __restrict__ h,
                            unsigned short* __restrict__ h_bf, int N) {
    int gid = blockIdx.x * blockDim.x + threadIdx.x;
    int n = gid >> 7, c = gid & 127;
    if (n >= N) return;
    const float* nrow = nf + (size_t)n * NODE_DIM;
    float acc = 0.f;
#pragma unroll 8
    for (int k = 0; k < NODE_DIM; ++k)
        acc += nrow[k] * W[k * H + c];
    acc += b[c];
    acc = fmaxf(acc, 0.f);
    h[(size_t)n * H + c] = acc;
    h_bf[(size_t)n * H + c] = f2bf(acc);
}

// ---------------- edge sort by dst: histogram, scan, scatter ----------------
__global__ void k_hist(const int* __restrict__ dst, int* __restrict__ deg_i, int E) {
    int e = blockIdx.x * blockDim.x + threadIdx.x;
    if (e < E) atomicAdd(&deg_i[dst[e]], 1);
}

__global__ __launch_bounds__(1024) void k_scan(const int* __restrict__ deg_i,
                                               int* __restrict__ row_start,
                                               int* __restrict__ cursor, int N) {
    __shared__ int part[1024];
    int t = threadIdx.x;
    int per = (N + 1023) / 1024;
    int base = t * per;
    int s = 0;
    for (int i = 0; i < per; ++i) {
        int idx = base + i;
        if (idx < N) s += deg_i[idx];
    }
    part[t] = s;
    __syncthreads();
    for (int off = 1; off < 1024; off <<= 1) {
        int v = (t >= off) ? part[t - off] : 0;
        __syncthreads();
        part[t] += v;
        __syncthreads();
    }
    int run = (t == 0) ? 0 : part[t - 1];
    for (int i = 0; i < per; ++i) {
        int idx = base + i;
        if (idx < N) {
            row_start[idx] = run;
            cursor[idx] = run;
            run += deg_i[idx];
        }
    }
    if (t == 1023) row_start[N] = run;
}

__global__ void k_sortscatter(const int* __restrict__ src, const int* __restrict__ dst,
                              int* __restrict__ cursor, int* __restrict__ es_src,
                              int* __restrict__ es_eid, int E) {
    int e = blockIdx.x * blockDim.x + threadIdx.x;
    if (e >= E) return;
    int pos = atomicAdd(&cursor[dst[e]], 1);
    es_src[pos] = src[e];
    es_eid[pos] = e;
}

// ---- permute edge features into dst-sorted order, bf16 (once) ----
__global__ void k_efsort(const float* __restrict__ ef, const int* __restrict__ es_eid,
                         unsigned short* __restrict__ efs_bf, int E) {
    int t = blockIdx.x * 256 + threadIdx.x;
    int p = t >> 2, q = t & 3;   // 4 threads/edge, 8 ch each
    if (p >= E) return;
    int eid = es_eid[p];
    const float* sp = ef + (size_t)eid * EDGE_DIM + q * 8;
    float4 v0 = *(const float4*)sp;
    float4 v1 = *(const float4*)(sp + 4);
    short8v o;
    o[0] = (short)f2bf(v0.x); o[1] = (short)f2bf(v0.y);
    o[2] = (short)f2bf(v0.z); o[3] = (short)f2bf(v0.w);
    o[4] = (short)f2bf(v1.x); o[5] = (short)f2bf(v1.y);
    o[6] = (short)f2bf(v1.z); o[7] = (short)f2bf(v1.w);
    *(short8v*)(efs_bf + (size_t)p * EDGE_DIM + q * 8) = o;
}

// ---------------- degree scalers ----------------
__global__ void k_scalers(const int* __restrict__ deg_i, float* __restrict__ invd,
                          float* __restrict__ amp, float* __restrict__ att, int N) {
    int n = blockIdx.x * blockDim.x + threadIdx.x;
    if (n >= N) return;
    float d = (float)deg_i[n];
    invd[n] = (d > 0.f) ? (1.f / d) : 0.f;
    float ld = logf(d + 1.f);
    amp[n] = ld;                                 // DELTA == 1.0
    att[n] = (d > 0.f) ? (1.f / ld) : 1.f;
}

// ------- weight conversion, ALL layers at once -------
// wf_post: K-blocks permuted for the 6-accumulator regrouping:
//   b:        0    1    2    3    4    5    6     7     8     9     10   11   12
//   W-row:    0    256  384  512  768  896  1024  1280  1408  1536  128  640  1152
//   (acc grp: 0    0    0    0    1    1    1     2     2     2     3    4    5)
__global__ void k_wconv_all(const float* __restrict__ pre_W,
                            const float* __restrict__ post_W,
                            short* __restrict__ wf_y_all,
                            short* __restrict__ wf_post_all,
                            short* __restrict__ wf_ef_all) {
    const int wrow[13] = {0, 256, 384, 512, 768, 896, 1024, 1280, 1408, 1536, 128, 640, 1152};
    int t = blockIdx.x * 256 + threadIdx.x;
    if (t < L_DEPTH * POST_FRAGS) {
        int l = t / POST_FRAGS, tt = t - l * POST_FRAGS;
        const float* qW = post_W + (size_t)l * KPOST * H;
        int lane = tt & 63, fc = tt >> 6;
        int b = fc >> 5, ks = (fc >> 3) & 3, cb = fc & 7;
        int col = cb * 16 + (lane & 15);
        int k0 = wrow[b] + ks * 32 + ((lane >> 4) << 3);
        short8v o;
#pragma unroll
        for (int j = 0; j < 8; ++j)
            o[j] = (short)f2bf(qW[(size_t)(k0 + j) * H + col]);
        *(short8v*)(wf_post_all + (size_t)t * 8) = o;
        return;
    }
    t -= L_DEPTH * POST_FRAGS;
    if (t < L_DEPTH * Y_FRAGS) {
        int l = t / Y_FRAGS, tt = t - l * Y_FRAGS;
        const float* pW = pre_W + (size_t)l * KPRE * H;
        int lane = tt & 63, fc = tt >> 6;
        int kglob = fc >> 4, cb = fc & 15;
        int col = cb * 16 + (lane & 15);          // 0..255
        int k0 = kglob * 32 + ((lane >> 4) << 3); // 0..127
        int rowoff = (col < 128) ? 0 : 128;
        int c = col & 127;
        short8v o;
#pragma unroll
        for (int j = 0; j < 8; ++j)
            o[j] = (short)f2bf(pW[(size_t)(rowoff + k0 + j) * H + c]);
        *(short8v*)(wf_y_all + (size_t)t * 8) = o;
        return;
    }
    t -= L_DEPTH * Y_FRAGS;
    if (t >= L_DEPTH * EF_FRAGS) return;
    int l = t / EF_FRAGS, tt = t - l * EF_FRAGS;
    int lane = tt & 63, cb = tt >> 6;             // 0..7
    int col = cb * 16 + (lane & 15);
    int k0 = (lane >> 4) << 3;
    const float* pW = pre_W + (size_t)l * KPRE * H;
    short8v o;
#pragma unroll
    for (int j = 0; j < 8; ++j)
        o[j] = (short)f2bf(pW[(size_t)(2 * H + k0 + j) * H + col]);
    *(short8v*)(wf_ef_all + (size_t)t * 8) = o;
}

// ---------------- Y1,Y2 (bf16) = h@W_src, h@W_dst via MFMA (layer 0 only) ----
__global__ __launch_bounds__(256) void k_ygemm_mfma(
    const unsigned short* __restrict__ h_bf, const short* __restrict__ Wf,
    unsigned short* __restrict__ Y1bf, unsigned short* __restrict__ Y2bf, int N)
{
    __shared__ __align__(16) short Xs[64 * 128];   // 16 KB, XOR-swizzled
    int tid = threadIdx.x;
    int n0 = blockIdx.x * 64;
    int lane = tid & 63, wave = tid >> 6;
    float4v acc[16];
#pragma unroll
    for (int cb = 0; cb < 16; ++cb) acc[cb] = (float4v){0.f, 0.f, 0.f, 0.f};

    int rs = tid >> 4, c0 = (tid & 15) * 8;
#pragma unroll
    for (int j = 0; j < 4; ++j) {
        int r = rs + j * 16;
        int n = n0 + r;
        uint4 v = make_uint4(0, 0, 0, 0);
        if (n < N) v = *(const uint4*)(h_bf + (size_t)n * H + c0);
        *(uint4*)((char*)Xs + r * 256 + ((c0 * 2) ^ ((r & 7) << 4))) = v;
    }
    __syncthreads();
    int rloc = wave * 16 + (lane & 15);
    int swz = (rloc & 7) << 4;
#pragma unroll
    for (int ks = 0; ks < 4; ++ks) {
        int boff = rloc * 256 + (((ks * 64) + ((lane >> 4) << 4)) ^ swz);
        short8v a = *(short8v*)((char*)Xs + boff);
        const short* wp = Wf + ((size_t)(ks * 16) * 64 + lane) * 8;
#pragma unroll
        for (int cb = 0; cb < 16; ++cb) {
            short8v b = *(const short8v*)(wp + (size_t)cb * 512);
            acc[cb] = __builtin_amdgcn_mfma_f32_16x16x32_bf16(a, b, acc[cb], 0, 0, 0);
        }
    }
    int col0 = lane & 15;
    int row0 = wave * 16 + ((lane >> 4) << 2);
#pragma unroll
    for (int cb = 0; cb < 16; ++cb) {
        int col = cb * 16 + col0;
#pragma unroll
        for (int r = 0; r < 4; ++r) {
            int n = n0 + row0 + r;
            if (n < N) {
                if (col < 128) Y1bf[(size_t)n * H + col] = f2bf(acc[cb][r]);
                else           Y2bf[(size_t)n * H + (col - 128)] = f2bf(acc[cb][r]);
            }
        }
    }
}

// ---------------- EFW[p][c] = efs[p] @ Wef (bf16, per layer) ----------------
__global__ __launch_bounds__(256) void k_efw(
    const unsigned short* __restrict__ efs_bf, const short* __restrict__ WfEf,
    unsigned short* __restrict__ EFW, int E)
{
    __shared__ __align__(16) unsigned short buf[4][16][128];   // 16 KB, wave-private
    int tid = threadIdx.x, lane = tid & 63, w = tid >> 6;
    int p0 = blockIdx.x * 256 + w * 64;
    short8v bfr[8];
#pragma unroll
    for (int cb = 0; cb < 8; ++cb)
        bfr[cb] = *(const short8v*)(WfEf + (size_t)(cb * 64 + lane) * 8);
#pragma unroll
    for (int t4 = 0; t4 < 4; ++t4) {
        int rowb = p0 + t4 * 16;
        int ar = rowb + (lane & 15);
        short8v a = {};
        if (ar < E)
            a = *(const short8v*)(efs_bf + (size_t)ar * EDGE_DIM + ((lane >> 4) << 3));
        float4v acc[8];
#pragma unroll
        for (int cb = 0; cb < 8; ++cb)
            acc[cb] = __builtin_amdgcn_mfma_f32_16x16x32_bf16(
                a, bfr[cb], (float4v){0.f, 0.f, 0.f, 0.f}, 0, 0, 0);
        // repack via wave-private LDS (DS ops are in-order per wave)
#pragma unroll
        for (int cb = 0; cb < 8; ++cb)
#pragma unroll
            for (int r = 0; r < 4; ++r)
                buf[w][((lane >> 4) << 2) + r][cb * 16 + (lane & 15)] = f2bf(acc[cb][r]);
#pragma unroll
        for (int j = 0; j < 4; ++j) {
            int lr = (lane >> 4) + j * 4;
            int gr = rowb + lr;
            uint4 v = *(const uint4*)&buf[w][lr][(lane & 15) * 8];
            if (gr < E)
                *(uint4*)(EFW + (size_t)gr * H + (lane & 15) * 8) = v;
        }
    }
}

// ------- aggregation: per node, reduce relu(Y1[src] + EFW[p] + Y2[n] + pb) -----
// 4 waves = 4 edge-quarters; each lane covers 2 channels (uint loads).
__global__ __launch_bounds__(256) void k_edge_agg(
    const unsigned short* __restrict__ Y1bf, const unsigned short* __restrict__ Y2bf,
    const unsigned short* __restrict__ EFW, const float* __restrict__ pb,
    const int* __restrict__ es_src, const int* __restrict__ row_start,
    unsigned short* __restrict__ s_out, unsigned short* __restrict__ mx_out,
    unsigned short* __restrict__ mn_out, int N)
{
    __shared__ float red[4][3][128];   // 6 KB
    int n = blockIdx.x;
    int tid = threadIdx.x, lane = tid & 63, w = tid >> 6;
    int start = row_start[n], end = row_start[n + 1];
    int cnt = end - start;
    int per = (cnt + 3) >> 2;
    int p0 = start + w * per;
    int p1 = min(p0 + per, end);
    unsigned int y2u = *(const unsigned int*)(Y2bf + (size_t)n * H + 2 * lane);
    float2 pbv = *(const float2*)(pb + 2 * lane);
    float y20 = bf2f((unsigned short)(y2u & 0xffffu)) + pbv.x;
    float y21 = bf2f((unsigned short)(y2u >> 16)) + pbv.y;
    float s0 = 0.f, s1 = 0.f;
    float mx0 = -3.4e38f, mx1 = -3.4e38f, mn0 = 3.4e38f, mn1 = 3.4e38f;
#pragma unroll 2
    for (int p = p0; p < p1; ++p) {
        int sn = __builtin_amdgcn_readfirstlane(es_src[p]);
        unsigned int y1u = *(const unsigned int*)(Y1bf + (size_t)sn * H + 2 * lane);
        unsigned int eu  = *(const unsigned int*)(EFW + (size_t)p * H + 2 * lane);
        float m0 = fmaxf(bf2f((unsigned short)(y1u & 0xffffu)) +
                         bf2f((unsigned short)(eu & 0xffffu)) + y20, 0.f);
        float m1 = fmaxf(bf2f((unsigned short)(y1u >> 16)) +
                         bf2f((unsigned short)(eu >> 16)) + y21, 0.f);
        s0 += m0; s1 += m1;
        mx0 = fmaxf(mx0, m0); mx1 = fmaxf(mx1, m1);
        mn0 = fminf(mn0, m0); mn1 = fminf(mn1, m1);
    }
    red[w][0][2 * lane] = s0;  red[w][0][2 * lane + 1] = s1;
    red[w][1][2 * lane] = mx0; red[w][1][2 * lane + 1] = mx1;
    red[w][2][2 * lane] = mn0; red[w][2][2 * lane + 1] = mn1;
    __syncthreads();
    if (tid < 128) {
        int c = tid;
        float s  = (red[0][0][c] + red[1][0][c]) + (red[2][0][c] + red[3][0][c]);
        float mx = fmaxf(fmaxf(red[0][1][c], red[1][1][c]),
                         fmaxf(red[2][1][c], red[3][1][c]));
        float mn = fminf(fminf(red[0][2][c], red[1][2][c]),
                         fminf(red[2][2][c], red[3][2][c]));
        if (cnt == 0) { s = 0.f; mx = 0.f; mn = 0.f; }
        size_t o = (size_t)n * H + c;
        s_out[o] = f2bf(s); mx_out[o] = f2bf(mx); mn_out[o] = f2bf(mn);
    }
}

// ------- posttrans via 6-group MFMA (no staging LDS, no scaling VALU) --------
// X@W regrouped: out = acc0 + amp*acc1 + att*acc2 + invd*(acc3 + amp*acc4 + att*acc5)
__global__ __launch_bounds__(256) void k_post_mfma(
    float* __restrict__ h, unsigned short* __restrict__ h_bf,
    const unsigned short* __restrict__ s_in, const unsigned short* __restrict__ mx_in,
    const unsigned short* __restrict__ mn_in,
    const float* __restrict__ invd, const float* __restrict__ amp,
    const float* __restrict__ att,
    const short* __restrict__ Wf, const float* __restrict__ qb,
    const short* __restrict__ WfY, unsigned short* __restrict__ Y1bf,
    unsigned short* __restrict__ Y2bf, int doY, int N)
{
    __shared__ __align__(16) short Xs[32 * 128];   // 8 KB, only for fused Y-GEMM
    int tid = threadIdx.x, lane = tid & 63, wave = tid >> 6;
    int rh = wave & 1, ch = wave >> 1;
    int n0 = blockIdx.x * 32;

    const unsigned short* const srcs[13] = {h_bf, mx_in, mn_in, s_in, mx_in, mn_in, s_in,
                                            mx_in, mn_in, s_in, s_in, s_in, s_in};
    const int grp_of[13] = {0, 0, 0, 0, 1, 1, 1, 2, 2, 2, 3, 4, 5};

    float4v acc[6][4];
#pragma unroll
    for (int g = 0; g < 6; ++g)
#pragma unroll
        for (int cb = 0; cb < 4; ++cb) acc[g][cb] = (float4v){0.f, 0.f, 0.f, 0.f};

    int arow = n0 + rh * 16 + (lane & 15);
    bool aok = arow < N;
    size_t abase = (size_t)arow * H + ((lane >> 4) << 3);

#pragma unroll
    for (int b = 0; b < 13; ++b) {
        const unsigned short* sp = srcs[b];
#pragma unroll
        for (int ks = 0; ks < 4; ++ks) {
            short8v a = {};
            if (aok) a = *(const short8v*)(sp + abase + ks * 32);
#pragma unroll
            for (int cb = 0; cb < 4; ++cb) {
                short8v bfrag = *(const short8v*)(
                    Wf + ((size_t)((b * 4 + ks) * 8 + ch * 4 + cb) * 64 + lane) * 8);
                acc[grp_of[b]][cb] =
                    __builtin_amdgcn_mfma_f32_16x16x32_bf16(a, bfrag, acc[grp_of[b]][cb], 0, 0, 0);
            }
        }
    }

    int col0 = lane & 15;
    int row0 = rh * 16 + ((lane >> 4) << 2);
    float s_invd[4], s_amp[4], s_att[4];
#pragma unroll
    for (int r = 0; r < 4; ++r) {
        int n = n0 + row0 + r;
        bool ok = n < N;
        s_invd[r] = ok ? invd[n] : 0.f;
        s_amp[r]  = ok ? amp[n]  : 0.f;
        s_att[r]  = ok ? att[n]  : 0.f;
    }
#pragma unroll
    for (int cb = 0; cb < 4; ++cb) {
        int col = (ch * 4 + cb) * 16 + col0;
        float bb = qb[col];
#pragma unroll
        for (int r = 0; r < 4; ++r) {
            int n = n0 + row0 + r;
            if (n < N) {
                float v = acc[0][cb][r]
                        + s_amp[r] * acc[1][cb][r] + s_att[r] * acc[2][cb][r]
                        + s_invd[r] * (acc[3][cb][r] + s_amp[r] * acc[4][cb][r]
                                       + s_att[r] * acc[5][cb][r]);
                size_t o = (size_t)n * H + col;
                float nv = h[o] + fmaxf(v + bb, 0.f);
                h[o] = nv;
                unsigned short us = f2bf(nv);
                h_bf[o] = us;
                if (doY) {
                    int rr = row0 + r;
                    *(short*)((char*)Xs + rr * 256 + ((col * 2) ^ ((rr & 7) << 4))) = (short)us;
                }
            }
        }
    }
    if (doY) {
        __syncthreads();
        // Y-GEMM: [32 x 128] @ [128 x 256]; wave handles cols wave*64..+63
        float4v yacc[8];
#pragma unroll
        for (int i = 0; i < 8; ++i) yacc[i] = (float4v){0.f, 0.f, 0.f, 0.f};
#pragma unroll
        for (int t16 = 0; t16 < 2; ++t16) {
            int rloc = t16 * 16 + (lane & 15);
            int swz = (rloc & 7) << 4;
#pragma unroll
            for (int ks = 0; ks < 4; ++ks) {
                int boff = rloc * 256 + (((ks * 64) + ((lane >> 4) << 4)) ^ swz);
                short8v a = *(short8v*)((char*)Xs + boff);
#pragma unroll
                for (int cb = 0; cb < 4; ++cb) {
                    const short* wp = WfY + ((size_t)(ks * 16 + wave * 4 + cb) * 64 + lane) * 8;
                    short8v b = *(const short8v*)wp;
                    yacc[t16 * 4 + cb] =
                        __builtin_amdgcn_mfma_f32_16x16x32_bf16(a, b, yacc[t16 * 4 + cb], 0, 0, 0);
                }
            }
        }
#pragma unroll
        for (int t16 = 0; t16 < 2; ++t16) {
#pragma unroll
            for (int cb = 0; cb < 4; ++cb) {
                int col = (wave * 4 + cb) * 16 + col0;
                int r0 = t16 * 16 + ((lane >> 4) << 2);
#pragma unroll
                for (int r = 0; r < 4; ++r) {
                    int n = n0 + r0 + r;
                    if (n < N) {
                        unsigned short v = f2bf(yacc[t16 * 4 + cb][r]);
                        if (col < 128) Y1bf[(size_t)n * H + col] = v;
                        else           Y2bf[(size_t)n * H + (col - 128)] = v;
                    }
                }
            }
        }
    }
}

// ---------------- graph readout scatter ----------------
__global__ void k_readout_scatter(const float* __restrict__ h, const int* __restrict__ n2g,
                                  float* __restrict__ g_sum, unsigned int* __restrict__ g_max,
                                  int N) {
    int gid = blockIdx.x * blockDim.x + threadIdx.x;
    int n = gid >> 7, c = gid & 127;
    if (n >= N) return;
    int g = n2g[n];
    float v = h[(size_t)n * H + c];
    atomicAdd(&g_sum[(size_t)g * H + c], v);
    atomicMax(&g_max[(size_t)g * H + c], __float_as_uint(v));  // h >= 0 always
}

__global__ void k_gcnt(const int* __restrict__ n2g, float* __restrict__ g_cnt, int N) {
    int n = blockIdx.x * blockDim.x + threadIdx.x;
    if (n < N) atomicAdd(&g_cnt[n2g[n]], 1.f);
}

// ---------------- final MLP ----------------
__global__ __launch_bounds__(256) void k_final(
    const float* __restrict__ g_sum, const float* __restrict__ g_max,
    const float* __restrict__ g_cnt,
    const float* __restrict__ W1, const float* __restrict__ b1,
    const float* __restrict__ W2, const float* __restrict__ b2,
    float* __restrict__ out)
{
    __shared__ float hid[H];
    int b = blockIdx.x, t = threadIdx.x;
    float cnt = g_cnt[b];
    if (t < H) {
        float acc = 0.f;
        float rc = 1.f / fmaxf(cnt, 1.f);
        for (int k = 0; k < 3 * H; ++k) {
            float x;
            if (k < H)          x = g_sum[(size_t)b * H + k] * rc;
            else if (k < 2 * H) x = (cnt > 0.f) ? g_max[(size_t)b * H + (k - H)] : 0.f;
            else                x = g_sum[(size_t)b * H + (k - 2 * H)];
            acc += x * W1[k * H + t];
        }
        hid[t] = fmaxf(acc + b1[t], 0.f);
    }
    __syncthreads();
    float acc = 0.f;
#pragma unroll 8
    for (int k = 0; k < H; ++k)
        acc += hid[k] * W2[k * T_OUT + t];
    out[(size_t)b * T_OUT + t] = acc + b2[t];
}

extern "C" void kernel_launch(void* const* d_in, const int* in_sizes, int n_in,
                              void* d_out, int out_size, void* d_ws, size_t ws_size,
                              hipStream_t stream) {
    const float* node_feat = (const float*)d_in[0];
    const float* edge_feat = (const float*)d_in[1];
    const float* W_in  = (const float*)d_in[2];
    const float* b_in  = (const float*)d_in[3];
    const float* pre_W = (const float*)d_in[4];
    const float* pre_b = (const float*)d_in[5];
    const float* post_W = (const float*)d_in[6];
    const float* post_b = (const float*)d_in[7];
    const float* out_W1 = (const float*)d_in[8];
    const float* out_b1 = (const float*)d_in[9];
    const float* out_W2 = (const float*)d_in[10];
    const float* out_b2 = (const float*)d_in[11];
    const int* src = (const int*)d_in[12];
    const int* dst = (const int*)d_in[13];
    const int* n2g = (const int*)d_in[14];

    int N = in_sizes[0] / NODE_DIM;
    int E = in_sizes[1] / EDGE_DIM;
    int B = out_size / T_OUT;
    float* out = (float*)d_out;

    float* ws = (float*)d_ws;
    float* h    = ws; ws += (size_t)N * H;
    float* invd = ws; ws += N;
    float* amp  = ws; ws += N;
    float* att  = ws; ws += N;
    float* g_sum = ws; ws += (size_t)B * H;
    unsigned int* g_max = (unsigned int*)ws; ws += (size_t)B * H;
    float* g_cnt = ws; ws += B;
    ws = (float*)(((uintptr_t)ws + 15) & ~(uintptr_t)15);
    unsigned short* h_bf  = (unsigned short*)ws;
    unsigned short* s_buf = h_bf  + (size_t)N * H;
    unsigned short* mx    = s_buf + (size_t)N * H;
    unsigned short* mn    = mx    + (size_t)N * H;
    unsigned short* Y1bf  = mn    + (size_t)N * H;
    unsigned short* Y2bf  = Y1bf  + (size_t)N * H;
    unsigned short* efs_bf = Y2bf + (size_t)N * H;
    unsigned short* EFW    = efs_bf + (size_t)E * EDGE_DIM;
    short* wf_post_all = (short*)(EFW + (size_t)E * H);
    short* wf_y_all    = wf_post_all + (size_t)L_DEPTH * POST_FRAGS * 8;
    short* wf_ef_all   = wf_y_all + (size_t)L_DEPTH * Y_FRAGS * 8;
    int* deg_i     = (int*)(wf_ef_all + (size_t)L_DEPTH * EF_FRAGS * 8);
    int* row_start = deg_i + N;
    int* cursor    = row_start + N + 1;
    int* es_src    = cursor + N;
    int* es_eid    = es_src + E;

    // input MLP (h fp32 + bf16 shadow)
    k_input_mlp<<<((size_t)N * H + 255) / 256, 256, 0, stream>>>(node_feat, W_in, b_in,
                                                                 h, h_bf, N);

    // edge sort by dst (dst static across layers)
    hipMemsetAsync(deg_i, 0, (size_t)N * sizeof(int), stream);
    k_hist<<<(E + 255) / 256, 256, 0, stream>>>(dst, deg_i, E);
    k_scan<<<1, 1024, 0, stream>>>(deg_i, row_start, cursor, N);
    k_sortscatter<<<(E + 255) / 256, 256, 0, stream>>>(src, dst, cursor, es_src, es_eid, E);
    k_efsort<<<((size_t)E * 4 + 255) / 256, 256, 0, stream>>>(edge_feat, es_eid, efs_bf, E);
    k_scalers<<<(N + 255) / 256, 256, 0, stream>>>(deg_i, invd, amp, att, N);

    // all-layer weight conversion (once)
    {
        int tot = L_DEPTH * (POST_FRAGS + Y_FRAGS + EF_FRAGS);
        k_wconv_all<<<(tot + 255) / 256, 256, 0, stream>>>(pre_W, post_W, wf_y_all,
                                                           wf_post_all, wf_ef_all);
    }

    // layer-0 Y GEMM
    k_ygemm_mfma<<<(N + 63) / 64, 256, 0, stream>>>(h_bf, wf_y_all, Y1bf, Y2bf, N);

    for (int l = 0; l < L_DEPTH; ++l) {
        k_efw<<<(E + 255) / 256, 256, 0, stream>>>(
            efs_bf, wf_ef_all + (size_t)l * EF_FRAGS * 8, EFW, E);
        k_edge_agg<<<N, 256, 0, stream>>>(
            Y1bf, Y2bf, EFW, pre_b + (size_t)l * H,
            es_src, row_start, s_buf, mx, mn, N);
        int doY = (l < L_DEPTH - 1) ? 1 : 0;
        k_post_mfma<<<(N + 31) / 32, 256, 0, stream>>>(
            h, h_bf, s_buf, mx, mn, invd, amp, att,
            wf_post_all + (size_t)l * POST_FRAGS * 8, post_b + (size_t)l * H,
            doY ? (wf_y_all + (size_t)(l + 1) * Y_FRAGS * 8) : wf_y_all,
            Y1bf, Y2bf, doY, N);
    }

    // readout
    hipMemsetAsync(g_sum, 0, (size_t)B * H * sizeof(float), stream);
    hipMemsetAsync(g_max, 0, (size_t)B * H * sizeof(float), stream);
    hipMemsetAsync(g_cnt, 0, (size_t)B * sizeof(float), stream);
    k_readout_scatter<<<((size_t)N * H + 255) / 256, 256, 0, stream>>>(h, n2g, g_sum, g_max, N);
    k_gcnt<<<(N + 255) / 256, 256, 0, stream>>>(n2g, g_cnt, N);
    k_final<<<B, 256, 0, stream>>>(g_sum, (const float*)g_max, g_cnt,
                                   out_W1, out_b1, out_W2, out_b2, out);
}

// Round 9
// 741.930 us; speedup vs baseline: 1.6527x; 1.1615x over previous
//
#include <hip/hip_runtime.h>

#define H 128
#define NODE_DIM 64
#define EDGE_DIM 32
#define KPRE (2*H + EDGE_DIM)   // 288
#define KPOST (13*H)            // 1664
#define T_OUT 256
#define L_DEPTH 5
#define POST_FRAGS (52*8*64)    // fragment-chunks per layer (posttrans W, permuted order)
#define Y_FRAGS (4*16*64)       // fragment-chunks per layer (ygemm W)
#define EF_FRAGS (8*64)         // fragment-chunks per layer (ef W)

typedef short short8v __attribute__((ext_vector_type(8)));
typedef float float4v __attribute__((ext_vector_type(4)));

__device__ __forceinline__ unsigned short f2bf(float x) {
    unsigned int b = __float_as_uint(x);
    return (unsigned short)((b + 0x7fffu + ((b >> 16) & 1u)) >> 16);  // RNE
}
__device__ __forceinline__ float bf2f(unsigned short u) {
    return __uint_as_float((unsigned int)u << 16);
}

// ---------------- input MLP: h = relu(node_feat @ W_in + b_in) ----------------
__global__ void k_input_mlp(const float* __restrict__ nf, const float* __restrict__ W,
                            const float* __restrict__ b, float* __restrict__ h,
                            unsigned short* __restrict__ h_bf, int N) {
    int gid = blockIdx.x * blockDim.x + threadIdx.x;
    int n = gid >> 7, c = gid & 127;
    if (n >= N) return;
    const float* nrow = nf + (size_t)n * NODE_DIM;
    float acc = 0.f;
#pragma unroll 8
    for (int k = 0; k < NODE_DIM; ++k)
        acc += nrow[k] * W[k * H + c];
    acc += b[c];
    acc = fmaxf(acc, 0.f);
    h[(size_t)n * H + c] = acc;
    h_bf[(size_t)n * H + c] = f2bf(acc);
}

// ---------------- edge sort by dst: histogram, scan, scatter ----------------
__global__ void k_hist(const int* __restrict__ dst, int* __restrict__ deg_i, int E) {
    int e = blockIdx.x * blockDim.x + threadIdx.x;
    if (e < E) atomicAdd(&deg_i[dst[e]], 1);
}

__global__ __launch_bounds__(1024) void k_scan(const int* __restrict__ deg_i,
                                               int* __restrict__ row_start,
                                               int* __restrict__ cursor, int N) {
    __shared__ int part[1024];
    int t = threadIdx.x;
    int per = (N + 1023) / 1024;
    int base = t * per;
    int s = 0;
    for (int i = 0; i < per; ++i) {
        int idx = base + i;
        if (idx < N) s += deg_i[idx];
    }
    part[t] = s;
    __syncthreads();
    for (int off = 1; off < 1024; off <<= 1) {
        int v = (t >= off) ? part[t - off] : 0;
        __syncthreads();
        part[t] += v;
        __syncthreads();
    }
    int run = (t == 0) ? 0 : part[t - 1];
    for (int i = 0; i < per; ++i) {
        int idx = base + i;
        if (idx < N) {
            row_start[idx] = run;
            cursor[idx] = run;
            run += deg_i[idx];
        }
    }
    if (t == 1023) row_start[N] = run;
}

__global__ void k_sortscatter(const int* __restrict__ src, const int* __restrict__ dst,
                              int* __restrict__ cursor, int* __restrict__ es_src,
                              int* __restrict__ es_eid, int E) {
    int e = blockIdx.x * blockDim.x + threadIdx.x;
    if (e >= E) return;
    int pos = atomicAdd(&cursor[dst[e]], 1);
    es_src[pos] = src[e];
    es_eid[pos] = e;
}

// ---- permute edge features into dst-sorted order, bf16 (once) ----
__global__ void k_efsort(const float* __restrict__ ef, const int* __restrict__ es_eid,
                         unsigned short* __restrict__ efs_bf, int E) {
    int t = blockIdx.x * 256 + threadIdx.x;
    int p = t >> 2, q = t & 3;   // 4 threads/edge, 8 ch each
    if (p >= E) return;
    int eid = es_eid[p];
    const float* sp = ef + (size_t)eid * EDGE_DIM + q * 8;
    float4 v0 = *(const float4*)sp;
    float4 v1 = *(const float4*)(sp + 4);
    short8v o;
    o[0] = (short)f2bf(v0.x); o[1] = (short)f2bf(v0.y);
    o[2] = (short)f2bf(v0.z); o[3] = (short)f2bf(v0.w);
    o[4] = (short)f2bf(v1.x); o[5] = (short)f2bf(v1.y);
    o[6] = (short)f2bf(v1.z); o[7] = (short)f2bf(v1.w);
    *(short8v*)(efs_bf + (size_t)p * EDGE_DIM + q * 8) = o;
}

// ---------------- degree scalers ----------------
__global__ void k_scalers(const int* __restrict__ deg_i, float* __restrict__ invd,
                          float* __restrict__ amp, float* __restrict__ att, int N) {
    int n = blockIdx.x * blockDim.x + threadIdx.x;
    if (n >= N) return;
    float d = (float)deg_i[n];
    invd[n] = (d > 0.f) ? (1.f / d) : 0.f;
    float ld = logf(d + 1.f);
    amp[n] = ld;                                 // DELTA == 1.0
    att[n] = (d > 0.f) ? (1.f / ld) : 1.f;
}

// ---- graph boundaries from SORTED n2g: g_start[g] = first n with n2g[n] >= g ----
__global__ void k_gbounds(const int* __restrict__ n2g, int* __restrict__ g_start,
                          int N, int B) {
    int n = blockIdx.x * 256 + threadIdx.x;
    if (n > N) return;
    int cur = (n < N) ? n2g[n] : B;
    int prev = (n == 0) ? -1 : n2g[n - 1];
    for (int g = prev + 1; g <= cur && g <= B; ++g)
        g_start[g] = n;
}

// ------- weight conversion, ALL layers at once -------
// wf_post: K-blocks permuted for the 6-accumulator regrouping:
//   b:        0    1    2    3    4    5    6     7     8     9     10   11   12
//   W-row:    0    256  384  512  768  896  1024  1280  1408  1536  128  640  1152
//   (acc grp: 0    0    0    0    1    1    1     2     2     2     3    4    5)
__global__ void k_wconv_all(const float* __restrict__ pre_W,
                            const float* __restrict__ post_W,
                            short* __restrict__ wf_y_all,
                            short* __restrict__ wf_post_all,
                            short* __restrict__ wf_ef_all) {
    const int wrow[13] = {0, 256, 384, 512, 768, 896, 1024, 1280, 1408, 1536, 128, 640, 1152};
    int t = blockIdx.x * 256 + threadIdx.x;
    if (t < L_DEPTH * POST_FRAGS) {
        int l = t / POST_FRAGS, tt = t - l * POST_FRAGS;
        const float* qW = post_W + (size_t)l * KPOST * H;
        int lane = tt & 63, fc = tt >> 6;
        int b = fc >> 5, ks = (fc >> 3) & 3, cb = fc & 7;
        int col = cb * 16 + (lane & 15);
        int k0 = wrow[b] + ks * 32 + ((lane >> 4) << 3);
        short8v o;
#pragma unroll
        for (int j = 0; j < 8; ++j)
            o[j] = (short)f2bf(qW[(size_t)(k0 + j) * H + col]);
        *(short8v*)(wf_post_all + (size_t)t * 8) = o;
        return;
    }
    t -= L_DEPTH * POST_FRAGS;
    if (t < L_DEPTH * Y_FRAGS) {
        int l = t / Y_FRAGS, tt = t - l * Y_FRAGS;
        const float* pW = pre_W + (size_t)l * KPRE * H;
        int lane = tt & 63, fc = tt >> 6;
        int kglob = fc >> 4, cb = fc & 15;
        int col = cb * 16 + (lane & 15);          // 0..255
        int k0 = kglob * 32 + ((lane >> 4) << 3); // 0..127
        int rowoff = (col < 128) ? 0 : 128;
        int c = col & 127;
        short8v o;
#pragma unroll
        for (int j = 0; j < 8; ++j)
            o[j] = (short)f2bf(pW[(size_t)(rowoff + k0 + j) * H + c]);
        *(short8v*)(wf_y_all + (size_t)t * 8) = o;
        return;
    }
    t -= L_DEPTH * Y_FRAGS;
    if (t >= L_DEPTH * EF_FRAGS) return;
    int l = t / EF_FRAGS, tt = t - l * EF_FRAGS;
    int lane = tt & 63, cb = tt >> 6;             // 0..7
    int col = cb * 16 + (lane & 15);
    int k0 = (lane >> 4) << 3;
    const float* pW = pre_W + (size_t)l * KPRE * H;
    short8v o;
#pragma unroll
    for (int j = 0; j < 8; ++j)
        o[j] = (short)f2bf(pW[(size_t)(2 * H + k0 + j) * H + col]);
    *(short8v*)(wf_ef_all + (size_t)t * 8) = o;
}

// ---------------- Y1,Y2 (bf16) = h@W_src, h@W_dst via MFMA (layer 0 only) ----
__global__ __launch_bounds__(256) void k_ygemm_mfma(
    const unsigned short* __restrict__ h_bf, const short* __restrict__ Wf,
    unsigned short* __restrict__ Y1bf, unsigned short* __restrict__ Y2bf, int N)
{
    __shared__ __align__(16) short Xs[64 * 128];   // 16 KB, XOR-swizzled
    int tid = threadIdx.x;
    int n0 = blockIdx.x * 64;
    int lane = tid & 63, wave = tid >> 6;
    float4v acc[16];
#pragma unroll
    for (int cb = 0; cb < 16; ++cb) acc[cb] = (float4v){0.f, 0.f, 0.f, 0.f};

    int rs = tid >> 4, c0 = (tid & 15) * 8;
#pragma unroll
    for (int j = 0; j < 4; ++j) {
        int r = rs + j * 16;
        int n = n0 + r;
        uint4 v = make_uint4(0, 0, 0, 0);
        if (n < N) v = *(const uint4*)(h_bf + (size_t)n * H + c0);
        *(uint4*)((char*)Xs + r * 256 + ((c0 * 2) ^ ((r & 7) << 4))) = v;
    }
    __syncthreads();
    int rloc = wave * 16 + (lane & 15);
    int swz = (rloc & 7) << 4;
#pragma unroll
    for (int ks = 0; ks < 4; ++ks) {
        int boff = rloc * 256 + (((ks * 64) + ((lane >> 4) << 4)) ^ swz);
        short8v a = *(short8v*)((char*)Xs + boff);
        const short* wp = Wf + ((size_t)(ks * 16) * 64 + lane) * 8;
#pragma unroll
        for (int cb = 0; cb < 16; ++cb) {
            short8v b = *(const short8v*)(wp + (size_t)cb * 512);
            acc[cb] = __builtin_amdgcn_mfma_f32_16x16x32_bf16(a, b, acc[cb], 0, 0, 0);
        }
    }
    int col0 = lane & 15;
    int row0 = wave * 16 + ((lane >> 4) << 2);
#pragma unroll
    for (int cb = 0; cb < 16; ++cb) {
        int col = cb * 16 + col0;
#pragma unroll
        for (int r = 0; r < 4; ++r) {
            int n = n0 + row0 + r;
            if (n < N) {
                if (col < 128) Y1bf[(size_t)n * H + col] = f2bf(acc[cb][r]);
                else           Y2bf[(size_t)n * H + (col - 128)] = f2bf(acc[cb][r]);
            }
        }
    }
}

// ---------------- EFW[p][c] = efs[p] @ Wef (bf16, per layer) ----------------
__global__ __launch_bounds__(256) void k_efw(
    const unsigned short* __restrict__ efs_bf, const short* __restrict__ WfEf,
    unsigned short* __restrict__ EFW, int E)
{
    __shared__ __align__(16) unsigned short buf[4][16][128];   // 16 KB, wave-private
    int tid = threadIdx.x, lane = tid & 63, w = tid >> 6;
    int p0 = blockIdx.x * 256 + w * 64;
    short8v bfr[8];
#pragma unroll
    for (int cb = 0; cb < 8; ++cb)
        bfr[cb] = *(const short8v*)(WfEf + (size_t)(cb * 64 + lane) * 8);
#pragma unroll
    for (int t4 = 0; t4 < 4; ++t4) {
        int rowb = p0 + t4 * 16;
        int ar = rowb + (lane & 15);
        short8v a = {};
        if (ar < E)
            a = *(const short8v*)(efs_bf + (size_t)ar * EDGE_DIM + ((lane >> 4) << 3));
        float4v acc[8];
#pragma unroll
        for (int cb = 0; cb < 8; ++cb)
            acc[cb] = __builtin_amdgcn_mfma_f32_16x16x32_bf16(
                a, bfr[cb], (float4v){0.f, 0.f, 0.f, 0.f}, 0, 0, 0);
        // repack via wave-private LDS (DS ops are in-order per wave)
#pragma unroll
        for (int cb = 0; cb < 8; ++cb)
#pragma unroll
            for (int r = 0; r < 4; ++r)
                buf[w][((lane >> 4) << 2) + r][cb * 16 + (lane & 15)] = f2bf(acc[cb][r]);
#pragma unroll
        for (int j = 0; j < 4; ++j) {
            int lr = (lane >> 4) + j * 4;
            int gr = rowb + lr;
            uint4 v = *(const uint4*)&buf[w][lr][(lane & 15) * 8];
            if (gr < E)
                *(uint4*)(EFW + (size_t)gr * H + (lane & 15) * 8) = v;
        }
    }
}

// ------- aggregation: per node, reduce relu(Y1[src] + EFW[p] + Y2[n] + pb) -----
// 4 waves = 4 edge-quarters; each lane covers 2 channels (uint loads).
__global__ __launch_bounds__(256) void k_edge_agg(
    const unsigned short* __restrict__ Y1bf, const unsigned short* __restrict__ Y2bf,
    const unsigned short* __restrict__ EFW, const float* __restrict__ pb,
    const int* __restrict__ es_src, const int* __restrict__ row_start,
    unsigned short* __restrict__ s_out, unsigned short* __restrict__ mx_out,
    unsigned short* __restrict__ mn_out, int N)
{
    __shared__ float red[4][3][128];   // 6 KB
    int n = blockIdx.x;
    int tid = threadIdx.x, lane = tid & 63, w = tid >> 6;
    int start = row_start[n], end = row_start[n + 1];
    int cnt = end - start;
    int per = (cnt + 3) >> 2;
    int p0 = start + w * per;
    int p1 = min(p0 + per, end);
    unsigned int y2u = *(const unsigned int*)(Y2bf + (size_t)n * H + 2 * lane);
    float2 pbv = *(const float2*)(pb + 2 * lane);
    float y20 = bf2f((unsigned short)(y2u & 0xffffu)) + pbv.x;
    float y21 = bf2f((unsigned short)(y2u >> 16)) + pbv.y;
    float s0 = 0.f, s1 = 0.f;
    float mx0 = -3.4e38f, mx1 = -3.4e38f, mn0 = 3.4e38f, mn1 = 3.4e38f;
#pragma unroll 2
    for (int p = p0; p < p1; ++p) {
        int sn = __builtin_amdgcn_readfirstlane(es_src[p]);
        unsigned int y1u = *(const unsigned int*)(Y1bf + (size_t)sn * H + 2 * lane);
        unsigned int eu  = *(const unsigned int*)(EFW + (size_t)p * H + 2 * lane);
        float m0 = fmaxf(bf2f((unsigned short)(y1u & 0xffffu)) +
                         bf2f((unsigned short)(eu & 0xffffu)) + y20, 0.f);
        float m1 = fmaxf(bf2f((unsigned short)(y1u >> 16)) +
                         bf2f((unsigned short)(eu >> 16)) + y21, 0.f);
        s0 += m0; s1 += m1;
        mx0 = fmaxf(mx0, m0); mx1 = fmaxf(mx1, m1);
        mn0 = fminf(mn0, m0); mn1 = fminf(mn1, m1);
    }
    red[w][0][2 * lane] = s0;  red[w][0][2 * lane + 1] = s1;
    red[w][1][2 * lane] = mx0; red[w][1][2 * lane + 1] = mx1;
    red[w][2][2 * lane] = mn0; red[w][2][2 * lane + 1] = mn1;
    __syncthreads();
    if (tid < 128) {
        int c = tid;
        float s  = (red[0][0][c] + red[1][0][c]) + (red[2][0][c] + red[3][0][c]);
        float mx = fmaxf(fmaxf(red[0][1][c], red[1][1][c]),
                         fmaxf(red[2][1][c], red[3][1][c]));
        float mn = fminf(fminf(red[0][2][c], red[1][2][c]),
                         fminf(red[2][2][c], red[3][2][c]));
        if (cnt == 0) { s = 0.f; mx = 0.f; mn = 0.f; }
        size_t o = (size_t)n * H + c;
        s_out[o] = f2bf(s); mx_out[o] = f2bf(mx); mn_out[o] = f2bf(mn);
    }
}

// ------- posttrans via 6-group MFMA (no staging LDS, no scaling VALU) --------
// X@W regrouped: out = acc0 + amp*acc1 + att*acc2 + invd*(acc3 + amp*acc4 + att*acc5)
__global__ __launch_bounds__(256) void k_post_mfma(
    float* __restrict__ h, unsigned short* __restrict__ h_bf,
    const unsigned short* __restrict__ s_in, const unsigned short* __restrict__ mx_in,
    const unsigned short* __restrict__ mn_in,
    const float* __restrict__ invd, const float* __restrict__ amp,
    const float* __restrict__ att,
    const short* __restrict__ Wf, const float* __restrict__ qb,
    const short* __restrict__ WfY, unsigned short* __restrict__ Y1bf,
    unsigned short* __restrict__ Y2bf, int doY, int N)
{
    __shared__ __align__(16) short Xs[32 * 128];   // 8 KB, only for fused Y-GEMM
    int tid = threadIdx.x, lane = tid & 63, wave = tid >> 6;
    int rh = wave & 1, ch = wave >> 1;
    int n0 = blockIdx.x * 32;

    const unsigned short* const srcs[13] = {h_bf, mx_in, mn_in, s_in, mx_in, mn_in, s_in,
                                            mx_in, mn_in, s_in, s_in, s_in, s_in};
    const int grp_of[13] = {0, 0, 0, 0, 1, 1, 1, 2, 2, 2, 3, 4, 5};

    float4v acc[6][4];
#pragma unroll
    for (int g = 0; g < 6; ++g)
#pragma unroll
        for (int cb = 0; cb < 4; ++cb) acc[g][cb] = (float4v){0.f, 0.f, 0.f, 0.f};

    int arow = n0 + rh * 16 + (lane & 15);
    bool aok = arow < N;
    size_t abase = (size_t)arow * H + ((lane >> 4) << 3);

#pragma unroll
    for (int b = 0; b < 13; ++b) {
        const unsigned short* sp = srcs[b];
#pragma unroll
        for (int ks = 0; ks < 4; ++ks) {
            short8v a = {};
            if (aok) a = *(const short8v*)(sp + abase + ks * 32);
#pragma unroll
            for (int cb = 0; cb < 4; ++cb) {
                short8v bfrag = *(const short8v*)(
                    Wf + ((size_t)((b * 4 + ks) * 8 + ch * 4 + cb) * 64 + lane) * 8);
                acc[grp_of[b]][cb] =
                    __builtin_amdgcn_mfma_f32_16x16x32_bf16(a, bfrag, acc[grp_of[b]][cb], 0, 0, 0);
            }
        }
    }

    int col0 = lane & 15;
    int row0 = rh * 16 + ((lane >> 4) << 2);
    float s_invd[4], s_amp[4], s_att[4];
#pragma unroll
    for (int r = 0; r < 4; ++r) {
        int n = n0 + row0 + r;
        bool ok = n < N;
        s_invd[r] = ok ? invd[n] : 0.f;
        s_amp[r]  = ok ? amp[n]  : 0.f;
        s_att[r]  = ok ? att[n]  : 0.f;
    }
#pragma unroll
    for (int cb = 0; cb < 4; ++cb) {
        int col = (ch * 4 + cb) * 16 + col0;
        float bb = qb[col];
#pragma unroll
        for (int r = 0; r < 4; ++r) {
            int n = n0 + row0 + r;
            if (n < N) {
                float v = acc[0][cb][r]
                        + s_amp[r] * acc[1][cb][r] + s_att[r] * acc[2][cb][r]
                        + s_invd[r] * (acc[3][cb][r] + s_amp[r] * acc[4][cb][r]
                                       + s_att[r] * acc[5][cb][r]);
                size_t o = (size_t)n * H + col;
                float nv = h[o] + fmaxf(v + bb, 0.f);
                h[o] = nv;
                unsigned short us = f2bf(nv);
                h_bf[o] = us;
                if (doY) {
                    int rr = row0 + r;
                    *(short*)((char*)Xs + rr * 256 + ((col * 2) ^ ((rr & 7) << 4))) = (short)us;
                }
            }
        }
    }
    if (doY) {
        __syncthreads();
        // Y-GEMM: [32 x 128] @ [128 x 256]; wave handles cols wave*64..+63
        float4v yacc[8];
#pragma unroll
        for (int i = 0; i < 8; ++i) yacc[i] = (float4v){0.f, 0.f, 0.f, 0.f};
#pragma unroll
        for (int t16 = 0; t16 < 2; ++t16) {
            int rloc = t16 * 16 + (lane & 15);
            int swz = (rloc & 7) << 4;
#pragma unroll
            for (int ks = 0; ks < 4; ++ks) {
                int boff = rloc * 256 + (((ks * 64) + ((lane >> 4) << 4)) ^ swz);
                short8v a = *(short8v*)((char*)Xs + boff);
#pragma unroll
                for (int cb = 0; cb < 4; ++cb) {
                    const short* wp = WfY + ((size_t)(ks * 16 + wave * 4 + cb) * 64 + lane) * 8;
                    short8v b = *(const short8v*)wp;
                    yacc[t16 * 4 + cb] =
                        __builtin_amdgcn_mfma_f32_16x16x32_bf16(a, b, yacc[t16 * 4 + cb], 0, 0, 0);
                }
            }
        }
#pragma unroll
        for (int t16 = 0; t16 < 2; ++t16) {
#pragma unroll
            for (int cb = 0; cb < 4; ++cb) {
                int col = (wave * 4 + cb) * 16 + col0;
                int r0 = t16 * 16 + ((lane >> 4) << 2);
#pragma unroll
                for (int r = 0; r < 4; ++r) {
                    int n = n0 + r0 + r;
                    if (n < N) {
                        unsigned short v = f2bf(yacc[t16 * 4 + cb][r]);
                        if (col < 128) Y1bf[(size_t)n * H + col] = v;
                        else           Y2bf[(size_t)n * H + (col - 128)] = v;
                    }
                }
            }
        }
    }
}

// ------- fused readout (segmented over sorted n2g) + final MLP, no atomics ----
__global__ __launch_bounds__(256) void k_readout_final(
    const float* __restrict__ h, const int* __restrict__ g_start,
    const float* __restrict__ W1, const float* __restrict__ b1,
    const float* __restrict__ W2, const float* __restrict__ b2,
    float* __restrict__ out)
{
    __shared__ float rs[2][128], rm[2][128];
    __shared__ float xv[3 * H];
    __shared__ float hid[H];
    int b = blockIdx.x, tid = threadIdx.x;
    int c = tid & 127, half = tid >> 7;
    int g0 = g_start[b], g1 = g_start[b + 1];
    int cnt = g1 - g0;
    float s = 0.f, m = -3.4e38f;
    for (int n = g0 + half; n < g1; n += 2) {
        float v = h[(size_t)n * H + c];
        s += v;
        m = fmaxf(m, v);
    }
    rs[half][c] = s;
    rm[half][c] = m;
    __syncthreads();
    if (tid < 128) {
        float ssum = rs[0][c] + rs[1][c];
        float mmax = fmaxf(rm[0][c], rm[1][c]);
        float rc = 1.f / fmaxf((float)cnt, 1.f);
        xv[c]           = ssum * rc;
        xv[H + c]       = (cnt > 0) ? mmax : 0.f;
        xv[2 * H + c]   = ssum;
    }
    __syncthreads();
    if (tid < 128) {
        float acc = 0.f;
        for (int k = 0; k < 3 * H; ++k)
            acc += xv[k] * W1[k * H + tid];
        hid[tid] = fmaxf(acc + b1[tid], 0.f);
    }
    __syncthreads();
    float acc = 0.f;
#pragma unroll 8
    for (int k = 0; k < H; ++k)
        acc += hid[k] * W2[k * T_OUT + tid];
    out[(size_t)b * T_OUT + tid] = acc + b2[tid];
}

extern "C" void kernel_launch(void* const* d_in, const int* in_sizes, int n_in,
                              void* d_out, int out_size, void* d_ws, size_t ws_size,
                              hipStream_t stream) {
    const float* node_feat = (const float*)d_in[0];
    const float* edge_feat = (const float*)d_in[1];
    const float* W_in  = (const float*)d_in[2];
    const float* b_in  = (const float*)d_in[3];
    const float* pre_W = (const float*)d_in[4];
    const float* pre_b = (const float*)d_in[5];
    const float* post_W = (const float*)d_in[6];
    const float* post_b = (const float*)d_in[7];
    const float* out_W1 = (const float*)d_in[8];
    const float* out_b1 = (const float*)d_in[9];
    const float* out_W2 = (const float*)d_in[10];
    const float* out_b2 = (const float*)d_in[11];
    const int* src = (const int*)d_in[12];
    const int* dst = (const int*)d_in[13];
    const int* n2g = (const int*)d_in[14];

    int N = in_sizes[0] / NODE_DIM;
    int E = in_sizes[1] / EDGE_DIM;
    int B = out_size / T_OUT;
    float* out = (float*)d_out;

    float* ws = (float*)d_ws;
    float* h    = ws; ws += (size_t)N * H;
    float* invd = ws; ws += N;
    float* amp  = ws; ws += N;
    float* att  = ws; ws += N;
    ws = (float*)(((uintptr_t)ws + 15) & ~(uintptr_t)15);
    unsigned short* h_bf  = (unsigned short*)ws;
    unsigned short* s_buf = h_bf  + (size_t)N * H;
    unsigned short* mx    = s_buf + (size_t)N * H;
    unsigned short* mn    = mx    + (size_t)N * H;
    unsigned short* Y1bf  = mn    + (size_t)N * H;
    unsigned short* Y2bf  = Y1bf  + (size_t)N * H;
    unsigned short* efs_bf = Y2bf + (size_t)N * H;
    unsigned short* EFW    = efs_bf + (size_t)E * EDGE_DIM;
    short* wf_post_all = (short*)(EFW + (size_t)E * H);
    short* wf_y_all    = wf_post_all + (size_t)L_DEPTH * POST_FRAGS * 8;
    short* wf_ef_all   = wf_y_all + (size_t)L_DEPTH * Y_FRAGS * 8;
    int* deg_i     = (int*)(wf_ef_all + (size_t)L_DEPTH * EF_FRAGS * 8);
    int* row_start = deg_i + N;
    int* cursor    = row_start + N + 1;
    int* es_src    = cursor + N;
    int* es_eid    = es_src + E;
    int* g_start   = es_eid + E;   // B+1 ints

    // input MLP (h fp32 + bf16 shadow)
    k_input_mlp<<<((size_t)N * H + 255) / 256, 256, 0, stream>>>(node_feat, W_in, b_in,
                                                                 h, h_bf, N);

    // edge sort by dst (dst static across layers)
    hipMemsetAsync(deg_i, 0, (size_t)N * sizeof(int), stream);
    k_hist<<<(E + 255) / 256, 256, 0, stream>>>(dst, deg_i, E);
    k_scan<<<1, 1024, 0, stream>>>(deg_i, row_start, cursor, N);
    k_sortscatter<<<(E + 255) / 256, 256, 0, stream>>>(src, dst, cursor, es_src, es_eid, E);
    k_efsort<<<((size_t)E * 4 + 255) / 256, 256, 0, stream>>>(edge_feat, es_eid, efs_bf, E);
    k_scalers<<<(N + 255) / 256, 256, 0, stream>>>(deg_i, invd, amp, att, N);
    k_gbounds<<<(N + 256) / 256, 256, 0, stream>>>(n2g, g_start, N, B);

    // all-layer weight conversion (once)
    {
        int tot = L_DEPTH * (POST_FRAGS + Y_FRAGS + EF_FRAGS);
        k_wconv_all<<<(tot + 255) / 256, 256, 0, stream>>>(pre_W, post_W, wf_y_all,
                                                           wf_post_all, wf_ef_all);
    }

    // layer-0 Y GEMM
    k_ygemm_mfma<<<(N + 63) / 64, 256, 0, stream>>>(h_bf, wf_y_all, Y1bf, Y2bf, N);

    for (int l = 0; l < L_DEPTH; ++l) {
        k_efw<<<(E + 255) / 256, 256, 0, stream>>>(
            efs_bf, wf_ef_all + (size_t)l * EF_FRAGS * 8, EFW, E);
        k_edge_agg<<<N, 256, 0, stream>>>(
            Y1bf, Y2bf, EFW, pre_b + (size_t)l * H,
            es_src, row_start, s_buf, mx, mn, N);
        int doY = (l < L_DEPTH - 1) ? 1 : 0;
        k_post_mfma<<<(N + 31) / 32, 256, 0, stream>>>(
            h, h_bf, s_buf, mx, mn, invd, amp, att,
            wf_post_all + (size_t)l * POST_FRAGS * 8, post_b + (size_t)l * H,
            doY ? (wf_y_all + (size_t)(l + 1) * Y_FRAGS * 8) : wf_y_all,
            Y1bf, Y2bf, doY, N);
    }

    // fused readout + final MLP (no atomics; n2g is sorted)
    k_readout_final<<<B, 256, 0, stream>>>(h, g_start, out_W1, out_b1, out_W2, out_b2, out);
}

// Round 10
// 715.254 us; speedup vs baseline: 1.7144x; 1.0373x over previous
//
#include <hip/hip_runtime.h>

#define H 128
#define NODE_DIM 64
#define EDGE_DIM 32
#define KPRE (2*H + EDGE_DIM)   // 288
#define KPOST (13*H)            // 1664
#define T_OUT 256
#define L_DEPTH 5
#define POST_FRAGS (52*8*64)    // fragment-chunks per layer (posttrans W, permuted order)
#define Y_FRAGS (4*16*64)       // fragment-chunks per layer (ygemm W)
#define EF_FRAGS (8*64)         // fragment-chunks per layer (ef W)
#define RCH 8                   // readout chunks per graph

typedef short short8v __attribute__((ext_vector_type(8)));
typedef float float4v __attribute__((ext_vector_type(4)));

__device__ __forceinline__ unsigned short f2bf(float x) {
    unsigned int b = __float_as_uint(x);
    return (unsigned short)((b + 0x7fffu + ((b >> 16) & 1u)) >> 16);  // RNE
}
__device__ __forceinline__ float bf2f(unsigned short u) {
    return __uint_as_float((unsigned int)u << 16);
}

// ---------------- input MLP: h = relu(node_feat @ W_in + b_in) ----------------
__global__ void k_input_mlp(const float* __restrict__ nf, const float* __restrict__ W,
                            const float* __restrict__ b, float* __restrict__ h,
                            unsigned short* __restrict__ h_bf, int N) {
    int gid = blockIdx.x * blockDim.x + threadIdx.x;
    int n = gid >> 7, c = gid & 127;
    if (n >= N) return;
    const float* nrow = nf + (size_t)n * NODE_DIM;
    float acc = 0.f;
#pragma unroll 8
    for (int k = 0; k < NODE_DIM; ++k)
        acc += nrow[k] * W[k * H + c];
    acc += b[c];
    acc = fmaxf(acc, 0.f);
    h[(size_t)n * H + c] = acc;
    h_bf[(size_t)n * H + c] = f2bf(acc);
}

// ---------------- edge sort by dst: histogram, scan, scatter ----------------
__global__ void k_hist(const int* __restrict__ dst, int* __restrict__ deg_i, int E) {
    int e = blockIdx.x * blockDim.x + threadIdx.x;
    if (e < E) atomicAdd(&deg_i[dst[e]], 1);
}

__global__ __launch_bounds__(1024) void k_scan(const int* __restrict__ deg_i,
                                               int* __restrict__ row_start,
                                               int* __restrict__ cursor, int N) {
    __shared__ int part[1024];
    int t = threadIdx.x;
    int per = (N + 1023) / 1024;
    int base = t * per;
    int s = 0;
    for (int i = 0; i < per; ++i) {
        int idx = base + i;
        if (idx < N) s += deg_i[idx];
    }
    part[t] = s;
    __syncthreads();
    for (int off = 1; off < 1024; off <<= 1) {
        int v = (t >= off) ? part[t - off] : 0;
        __syncthreads();
        part[t] += v;
        __syncthreads();
    }
    int run = (t == 0) ? 0 : part[t - 1];
    for (int i = 0; i < per; ++i) {
        int idx = base + i;
        if (idx < N) {
            row_start[idx] = run;
            cursor[idx] = run;
            run += deg_i[idx];
        }
    }
    if (t == 1023) row_start[N] = run;
}

__global__ void k_sortscatter(const int* __restrict__ src, const int* __restrict__ dst,
                              int* __restrict__ cursor, int* __restrict__ es_src,
                              int* __restrict__ es_eid, int E) {
    int e = blockIdx.x * blockDim.x + threadIdx.x;
    if (e >= E) return;
    int pos = atomicAdd(&cursor[dst[e]], 1);
    es_src[pos] = src[e];
    es_eid[pos] = e;
}

// ---- permute edge features into dst-sorted order, bf16 (once) ----
__global__ void k_efsort(const float* __restrict__ ef, const int* __restrict__ es_eid,
                         unsigned short* __restrict__ efs_bf, int E) {
    int t = blockIdx.x * 256 + threadIdx.x;
    int p = t >> 2, q = t & 3;   // 4 threads/edge, 8 ch each
    if (p >= E) return;
    int eid = es_eid[p];
    const float* sp = ef + (size_t)eid * EDGE_DIM + q * 8;
    float4 v0 = *(const float4*)sp;
    float4 v1 = *(const float4*)(sp + 4);
    short8v o;
    o[0] = (short)f2bf(v0.x); o[1] = (short)f2bf(v0.y);
    o[2] = (short)f2bf(v0.z); o[3] = (short)f2bf(v0.w);
    o[4] = (short)f2bf(v1.x); o[5] = (short)f2bf(v1.y);
    o[6] = (short)f2bf(v1.z); o[7] = (short)f2bf(v1.w);
    *(short8v*)(efs_bf + (size_t)p * EDGE_DIM + q * 8) = o;
}

// ---------------- degree scalers ----------------
__global__ void k_scalers(const int* __restrict__ deg_i, float* __restrict__ invd,
                          float* __restrict__ amp, float* __restrict__ att, int N) {
    int n = blockIdx.x * blockDim.x + threadIdx.x;
    if (n >= N) return;
    float d = (float)deg_i[n];
    invd[n] = (d > 0.f) ? (1.f / d) : 0.f;
    float ld = logf(d + 1.f);
    amp[n] = ld;                                 // DELTA == 1.0
    att[n] = (d > 0.f) ? (1.f / ld) : 1.f;
}

// ---- graph boundaries from SORTED n2g: g_start[g] = first n with n2g[n] >= g ----
__global__ void k_gbounds(const int* __restrict__ n2g, int* __restrict__ g_start,
                          int N, int B) {
    int n = blockIdx.x * 256 + threadIdx.x;
    if (n > N) return;
    int cur = (n < N) ? n2g[n] : B;
    int prev = (n == 0) ? -1 : n2g[n - 1];
    for (int g = prev + 1; g <= cur && g <= B; ++g)
        g_start[g] = n;
}

// ------- weight conversion, ALL layers at once -------
// wf_post: K-blocks permuted for the 6-accumulator regrouping:
//   b:        0    1    2    3    4    5    6     7     8     9     10   11   12
//   W-row:    0    256  384  512  768  896  1024  1280  1408  1536  128  640  1152
//   (acc grp: 0    0    0    0    1    1    1     2     2     2     3    4    5)
__global__ void k_wconv_all(const float* __restrict__ pre_W,
                            const float* __restrict__ post_W,
                            short* __restrict__ wf_y_all,
                            short* __restrict__ wf_post_all,
                            short* __restrict__ wf_ef_all) {
    const int wrow[13] = {0, 256, 384, 512, 768, 896, 1024, 1280, 1408, 1536, 128, 640, 1152};
    int t = blockIdx.x * 256 + threadIdx.x;
    if (t < L_DEPTH * POST_FRAGS) {
        int l = t / POST_FRAGS, tt = t - l * POST_FRAGS;
        const float* qW = post_W + (size_t)l * KPOST * H;
        int lane = tt & 63, fc = tt >> 6;
        int b = fc >> 5, ks = (fc >> 3) & 3, cb = fc & 7;
        int col = cb * 16 + (lane & 15);
        int k0 = wrow[b] + ks * 32 + ((lane >> 4) << 3);
        short8v o;
#pragma unroll
        for (int j = 0; j < 8; ++j)
            o[j] = (short)f2bf(qW[(size_t)(k0 + j) * H + col]);
        *(short8v*)(wf_post_all + (size_t)t * 8) = o;
        return;
    }
    t -= L_DEPTH * POST_FRAGS;
    if (t < L_DEPTH * Y_FRAGS) {
        int l = t / Y_FRAGS, tt = t - l * Y_FRAGS;
        const float* pW = pre_W + (size_t)l * KPRE * H;
        int lane = tt & 63, fc = tt >> 6;
        int kglob = fc >> 4, cb = fc & 15;
        int col = cb * 16 + (lane & 15);          // 0..255
        int k0 = kglob * 32 + ((lane >> 4) << 3); // 0..127
        int rowoff = (col < 128) ? 0 : 128;
        int c = col & 127;
        short8v o;
#pragma unroll
        for (int j = 0; j < 8; ++j)
            o[j] = (short)f2bf(pW[(size_t)(rowoff + k0 + j) * H + c]);
        *(short8v*)(wf_y_all + (size_t)t * 8) = o;
        return;
    }
    t -= L_DEPTH * Y_FRAGS;
    if (t >= L_DEPTH * EF_FRAGS) return;
    int l = t / EF_FRAGS, tt = t - l * EF_FRAGS;
    int lane = tt & 63, cb = tt >> 6;             // 0..7
    int col = cb * 16 + (lane & 15);
    int k0 = (lane >> 4) << 3;
    const float* pW = pre_W + (size_t)l * KPRE * H;
    short8v o;
#pragma unroll
    for (int j = 0; j < 8; ++j)
        o[j] = (short)f2bf(pW[(size_t)(2 * H + k0 + j) * H + col]);
    *(short8v*)(wf_ef_all + (size_t)t * 8) = o;
}

// ---------------- Y1,Y2 (bf16) = h@W_src, h@W_dst via MFMA (layer 0 only) ----
__global__ __launch_bounds__(256) void k_ygemm_mfma(
    const unsigned short* __restrict__ h_bf, const short* __restrict__ Wf,
    unsigned short* __restrict__ Y1bf, unsigned short* __restrict__ Y2bf, int N)
{
    __shared__ __align__(16) short Xs[64 * 128];   // 16 KB, XOR-swizzled
    int tid = threadIdx.x;
    int n0 = blockIdx.x * 64;
    int lane = tid & 63, wave = tid >> 6;
    float4v acc[16];
#pragma unroll
    for (int cb = 0; cb < 16; ++cb) acc[cb] = (float4v){0.f, 0.f, 0.f, 0.f};

    int rs = tid >> 4, c0 = (tid & 15) * 8;
#pragma unroll
    for (int j = 0; j < 4; ++j) {
        int r = rs + j * 16;
        int n = n0 + r;
        uint4 v = make_uint4(0, 0, 0, 0);
        if (n < N) v = *(const uint4*)(h_bf + (size_t)n * H + c0);
        *(uint4*)((char*)Xs + r * 256 + ((c0 * 2) ^ ((r & 7) << 4))) = v;
    }
    __syncthreads();
    int rloc = wave * 16 + (lane & 15);
    int swz = (rloc & 7) << 4;
#pragma unroll
    for (int ks = 0; ks < 4; ++ks) {
        int boff = rloc * 256 + (((ks * 64) + ((lane >> 4) << 4)) ^ swz);
        short8v a = *(short8v*)((char*)Xs + boff);
        const short* wp = Wf + ((size_t)(ks * 16) * 64 + lane) * 8;
#pragma unroll
        for (int cb = 0; cb < 16; ++cb) {
            short8v b = *(const short8v*)(wp + (size_t)cb * 512);
            acc[cb] = __builtin_amdgcn_mfma_f32_16x16x32_bf16(a, b, acc[cb], 0, 0, 0);
        }
    }
    int col0 = lane & 15;
    int row0 = wave * 16 + ((lane >> 4) << 2);
#pragma unroll
    for (int cb = 0; cb < 16; ++cb) {
        int col = cb * 16 + col0;
#pragma unroll
        for (int r = 0; r < 4; ++r) {
            int n = n0 + row0 + r;
            if (n < N) {
                if (col < 128) Y1bf[(size_t)n * H + col] = f2bf(acc[cb][r]);
                else           Y2bf[(size_t)n * H + (col - 128)] = f2bf(acc[cb][r]);
            }
        }
    }
}

// ---------------- EFW[p][c] = efs[p] @ Wef (bf16, per layer) ----------------
__global__ __launch_bounds__(256) void k_efw(
    const unsigned short* __restrict__ efs_bf, const short* __restrict__ WfEf,
    unsigned short* __restrict__ EFW, int E)
{
    __shared__ __align__(16) unsigned short buf[4][16][128];   // 16 KB, wave-private
    int tid = threadIdx.x, lane = tid & 63, w = tid >> 6;
    int p0 = blockIdx.x * 256 + w * 64;
    short8v bfr[8];
#pragma unroll
    for (int cb = 0; cb < 8; ++cb)
        bfr[cb] = *(const short8v*)(WfEf + (size_t)(cb * 64 + lane) * 8);
#pragma unroll
    for (int t4 = 0; t4 < 4; ++t4) {
        int rowb = p0 + t4 * 16;
        int ar = rowb + (lane & 15);
        short8v a = {};
        if (ar < E)
            a = *(const short8v*)(efs_bf + (size_t)ar * EDGE_DIM + ((lane >> 4) << 3));
        float4v acc[8];
#pragma unroll
        for (int cb = 0; cb < 8; ++cb)
            acc[cb] = __builtin_amdgcn_mfma_f32_16x16x32_bf16(
                a, bfr[cb], (float4v){0.f, 0.f, 0.f, 0.f}, 0, 0, 0);
        // repack via wave-private LDS (DS ops are in-order per wave)
#pragma unroll
        for (int cb = 0; cb < 8; ++cb)
#pragma unroll
            for (int r = 0; r < 4; ++r)
                buf[w][((lane >> 4) << 2) + r][cb * 16 + (lane & 15)] = f2bf(acc[cb][r]);
#pragma unroll
        for (int j = 0; j < 4; ++j) {
            int lr = (lane >> 4) + j * 4;
            int gr = rowb + lr;
            uint4 v = *(const uint4*)&buf[w][lr][(lane & 15) * 8];
            if (gr < E)
                *(uint4*)(EFW + (size_t)gr * H + (lane & 15) * 8) = v;
        }
    }
}

// ------- aggregation: per node, reduce relu(Y1[src] + EFW[p] + Y2[n] + pb) -----
// 4 waves = 4 edge-quarters; each lane covers 2 channels (uint loads).
__global__ __launch_bounds__(256) void k_edge_agg(
    const unsigned short* __restrict__ Y1bf, const unsigned short* __restrict__ Y2bf,
    const unsigned short* __restrict__ EFW, const float* __restrict__ pb,
    const int* __restrict__ es_src, const int* __restrict__ row_start,
    unsigned short* __restrict__ s_out, unsigned short* __restrict__ mx_out,
    unsigned short* __restrict__ mn_out, int N)
{
    __shared__ float red[4][3][128];   // 6 KB
    int n = blockIdx.x;
    int tid = threadIdx.x, lane = tid & 63, w = tid >> 6;
    int start = row_start[n], end = row_start[n + 1];
    int cnt = end - start;
    int per = (cnt + 3) >> 2;
    int p0 = start + w * per;
    int p1 = min(p0 + per, end);
    unsigned int y2u = *(const unsigned int*)(Y2bf + (size_t)n * H + 2 * lane);
    float2 pbv = *(const float2*)(pb + 2 * lane);
    float y20 = bf2f((unsigned short)(y2u & 0xffffu)) + pbv.x;
    float y21 = bf2f((unsigned short)(y2u >> 16)) + pbv.y;
    float s0 = 0.f, s1 = 0.f;
    float mx0 = -3.4e38f, mx1 = -3.4e38f, mn0 = 3.4e38f, mn1 = 3.4e38f;
#pragma unroll 2
    for (int p = p0; p < p1; ++p) {
        int sn = __builtin_amdgcn_readfirstlane(es_src[p]);
        unsigned int y1u = *(const unsigned int*)(Y1bf + (size_t)sn * H + 2 * lane);
        unsigned int eu  = *(const unsigned int*)(EFW + (size_t)p * H + 2 * lane);
        float m0 = fmaxf(bf2f((unsigned short)(y1u & 0xffffu)) +
                         bf2f((unsigned short)(eu & 0xffffu)) + y20, 0.f);
        float m1 = fmaxf(bf2f((unsigned short)(y1u >> 16)) +
                         bf2f((unsigned short)(eu >> 16)) + y21, 0.f);
        s0 += m0; s1 += m1;
        mx0 = fmaxf(mx0, m0); mx1 = fmaxf(mx1, m1);
        mn0 = fminf(mn0, m0); mn1 = fminf(mn1, m1);
    }
    red[w][0][2 * lane] = s0;  red[w][0][2 * lane + 1] = s1;
    red[w][1][2 * lane] = mx0; red[w][1][2 * lane + 1] = mx1;
    red[w][2][2 * lane] = mn0; red[w][2][2 * lane + 1] = mn1;
    __syncthreads();
    if (tid < 128) {
        int c = tid;
        float s  = (red[0][0][c] + red[1][0][c]) + (red[2][0][c] + red[3][0][c]);
        float mx = fmaxf(fmaxf(red[0][1][c], red[1][1][c]),
                         fmaxf(red[2][1][c], red[3][1][c]));
        float mn = fminf(fminf(red[0][2][c], red[1][2][c]),
                         fminf(red[2][2][c], red[3][2][c]));
        if (cnt == 0) { s = 0.f; mx = 0.f; mn = 0.f; }
        size_t o = (size_t)n * H + c;
        s_out[o] = f2bf(s); mx_out[o] = f2bf(mx); mn_out[o] = f2bf(mn);
    }
}

// ------- posttrans via 6-group MFMA (no staging LDS, no scaling VALU) --------
// X@W regrouped: out = acc0 + amp*acc1 + att*acc2 + invd*(acc3 + amp*acc4 + att*acc5)
__global__ __launch_bounds__(256) void k_post_mfma(
    float* __restrict__ h, unsigned short* __restrict__ h_bf,
    const unsigned short* __restrict__ s_in, const unsigned short* __restrict__ mx_in,
    const unsigned short* __restrict__ mn_in,
    const float* __restrict__ invd, const float* __restrict__ amp,
    const float* __restrict__ att,
    const short* __restrict__ Wf, const float* __restrict__ qb,
    const short* __restrict__ WfY, unsigned short* __restrict__ Y1bf,
    unsigned short* __restrict__ Y2bf, int doY, int N)
{
    __shared__ __align__(16) short Xs[32 * 128];   // 8 KB, only for fused Y-GEMM
    int tid = threadIdx.x, lane = tid & 63, wave = tid >> 6;
    int rh = wave & 1, ch = wave >> 1;
    int n0 = blockIdx.x * 32;

    const unsigned short* const srcs[13] = {h_bf, mx_in, mn_in, s_in, mx_in, mn_in, s_in,
                                            mx_in, mn_in, s_in, s_in, s_in, s_in};
    const int grp_of[13] = {0, 0, 0, 0, 1, 1, 1, 2, 2, 2, 3, 4, 5};

    float4v acc[6][4];
#pragma unroll
    for (int g = 0; g < 6; ++g)
#pragma unroll
        for (int cb = 0; cb < 4; ++cb) acc[g][cb] = (float4v){0.f, 0.f, 0.f, 0.f};

    int arow = n0 + rh * 16 + (lane & 15);
    bool aok = arow < N;
    size_t abase = (size_t)arow * H + ((lane >> 4) << 3);

#pragma unroll
    for (int b = 0; b < 13; ++b) {
        const unsigned short* sp = srcs[b];
#pragma unroll
        for (int ks = 0; ks < 4; ++ks) {
            short8v a = {};
            if (aok) a = *(const short8v*)(sp + abase + ks * 32);
#pragma unroll
            for (int cb = 0; cb < 4; ++cb) {
                short8v bfrag = *(const short8v*)(
                    Wf + ((size_t)((b * 4 + ks) * 8 + ch * 4 + cb) * 64 + lane) * 8);
                acc[grp_of[b]][cb] =
                    __builtin_amdgcn_mfma_f32_16x16x32_bf16(a, bfrag, acc[grp_of[b]][cb], 0, 0, 0);
            }
        }
    }

    int col0 = lane & 15;
    int row0 = rh * 16 + ((lane >> 4) << 2);
    float s_invd[4], s_amp[4], s_att[4];
#pragma unroll
    for (int r = 0; r < 4; ++r) {
        int n = n0 + row0 + r;
        bool ok = n < N;
        s_invd[r] = ok ? invd[n] : 0.f;
        s_amp[r]  = ok ? amp[n]  : 0.f;
        s_att[r]  = ok ? att[n]  : 0.f;
    }
#pragma unroll
    for (int cb = 0; cb < 4; ++cb) {
        int col = (ch * 4 + cb) * 16 + col0;
        float bb = qb[col];
#pragma unroll
        for (int r = 0; r < 4; ++r) {
            int n = n0 + row0 + r;
            if (n < N) {
                float v = acc[0][cb][r]
                        + s_amp[r] * acc[1][cb][r] + s_att[r] * acc[2][cb][r]
                        + s_invd[r] * (acc[3][cb][r] + s_amp[r] * acc[4][cb][r]
                                       + s_att[r] * acc[5][cb][r]);
                size_t o = (size_t)n * H + col;
                float nv = h[o] + fmaxf(v + bb, 0.f);
                h[o] = nv;
                unsigned short us = f2bf(nv);
                h_bf[o] = us;
                if (doY) {
                    int rr = row0 + r;
                    *(short*)((char*)Xs + rr * 256 + ((col * 2) ^ ((rr & 7) << 4))) = (short)us;
                }
            }
        }
    }
    if (doY) {
        __syncthreads();
        // Y-GEMM: [32 x 128] @ [128 x 256]; wave handles cols wave*64..+63
        float4v yacc[8];
#pragma unroll
        for (int i = 0; i < 8; ++i) yacc[i] = (float4v){0.f, 0.f, 0.f, 0.f};
#pragma unroll
        for (int t16 = 0; t16 < 2; ++t16) {
            int rloc = t16 * 16 + (lane & 15);
            int swz = (rloc & 7) << 4;
#pragma unroll
            for (int ks = 0; ks < 4; ++ks) {
                int boff = rloc * 256 + (((ks * 64) + ((lane >> 4) << 4)) ^ swz);
                short8v a = *(short8v*)((char*)Xs + boff);
#pragma unroll
                for (int cb = 0; cb < 4; ++cb) {
                    const short* wp = WfY + ((size_t)(ks * 16 + wave * 4 + cb) * 64 + lane) * 8;
                    short8v b = *(const short8v*)wp;
                    yacc[t16 * 4 + cb] =
                        __builtin_amdgcn_mfma_f32_16x16x32_bf16(a, b, yacc[t16 * 4 + cb], 0, 0, 0);
                }
            }
        }
#pragma unroll
        for (int t16 = 0; t16 < 2; ++t16) {
#pragma unroll
            for (int cb = 0; cb < 4; ++cb) {
                int col = (wave * 4 + cb) * 16 + col0;
                int r0 = t16 * 16 + ((lane >> 4) << 2);
#pragma unroll
                for (int r = 0; r < 4; ++r) {
                    int n = n0 + r0 + r;
                    if (n < N) {
                        unsigned short v = f2bf(yacc[t16 * 4 + cb][r]);
                        if (col < 128) Y1bf[(size_t)n * H + col] = v;
                        else           Y2bf[(size_t)n * H + (col - 128)] = v;
                    }
                }
            }
        }
    }
}

// ------- readout stage 1: partial sum/max per (graph, chunk) — no atomics ----
__global__ __launch_bounds__(256) void k_readout_part(
    const float* __restrict__ h, const int* __restrict__ g_start,
    float* __restrict__ psum, float* __restrict__ pmax, int B)
{
    __shared__ float rs[2][128], rm[2][128];
    int blk = blockIdx.x;
    int b = blk / RCH, chunk = blk % RCH;
    int tid = threadIdx.x;
    int c = tid & 127, half = tid >> 7;
    int g0 = g_start[b], g1 = g_start[b + 1];
    int cnt = g1 - g0;
    int per = (cnt + RCH - 1) / RCH;
    int n0 = g0 + chunk * per;
    int n1 = min(n0 + per, g1);
    float s = 0.f, m = -3.4e38f;
    for (int n = n0 + half; n < n1; n += 2) {
        float v = h[(size_t)n * H + c];
        s += v;
        m = fmaxf(m, v);
    }
    rs[half][c] = s;
    rm[half][c] = m;
    __syncthreads();
    if (tid < 128) {
        size_t o = ((size_t)b * RCH + chunk) * H + c;
        psum[o] = rs[0][c] + rs[1][c];
        pmax[o] = fmaxf(rm[0][c], rm[1][c]);
    }
}

// ------- readout stage 2: combine partials + final MLP ----------------------
__global__ __launch_bounds__(256) void k_readout_final2(
    const float* __restrict__ psum, const float* __restrict__ pmax,
    const int* __restrict__ g_start,
    const float* __restrict__ W1, const float* __restrict__ b1,
    const float* __restrict__ W2, const float* __restrict__ b2,
    float* __restrict__ out)
{
    __shared__ float xv[3 * H];
    __shared__ float hid[H];
    int b = blockIdx.x, tid = threadIdx.x;
    int cnt = g_start[b + 1] - g_start[b];
    if (tid < 128) {
        int c = tid;
        float s = 0.f, m = -3.4e38f;
#pragma unroll
        for (int j = 0; j < RCH; ++j) {
            size_t o = ((size_t)b * RCH + j) * H + c;
            s += psum[o];
            m = fmaxf(m, pmax[o]);
        }
        float rc = 1.f / fmaxf((float)cnt, 1.f);
        xv[c]         = s * rc;
        xv[H + c]     = (cnt > 0) ? m : 0.f;
        xv[2 * H + c] = s;
    }
    __syncthreads();
    if (tid < 128) {
        float acc = 0.f;
        for (int k = 0; k < 3 * H; ++k)
            acc += xv[k] * W1[k * H + tid];
        hid[tid] = fmaxf(acc + b1[tid], 0.f);
    }
    __syncthreads();
    float acc = 0.f;
#pragma unroll 8
    for (int k = 0; k < H; ++k)
        acc += hid[k] * W2[k * T_OUT + tid];
    out[(size_t)b * T_OUT + tid] = acc + b2[tid];
}

extern "C" void kernel_launch(void* const* d_in, const int* in_sizes, int n_in,
                              void* d_out, int out_size, void* d_ws, size_t ws_size,
                              hipStream_t stream) {
    const float* node_feat = (const float*)d_in[0];
    const float* edge_feat = (const float*)d_in[1];
    const float* W_in  = (const float*)d_in[2];
    const float* b_in  = (const float*)d_in[3];
    const float* pre_W = (const float*)d_in[4];
    const float* pre_b = (const float*)d_in[5];
    const float* post_W = (const float*)d_in[6];
    const float* post_b = (const float*)d_in[7];
    const float* out_W1 = (const float*)d_in[8];
    const float* out_b1 = (const float*)d_in[9];
    const float* out_W2 = (const float*)d_in[10];
    const float* out_b2 = (const float*)d_in[11];
    const int* src = (const int*)d_in[12];
    const int* dst = (const int*)d_in[13];
    const int* n2g = (const int*)d_in[14];

    int N = in_sizes[0] / NODE_DIM;
    int E = in_sizes[1] / EDGE_DIM;
    int B = out_size / T_OUT;
    float* out = (float*)d_out;

    float* ws = (float*)d_ws;
    float* h    = ws; ws += (size_t)N * H;
    float* invd = ws; ws += N;
    float* amp  = ws; ws += N;
    float* att  = ws; ws += N;
    float* psum = ws; ws += (size_t)B * RCH * H;
    float* pmax = ws; ws += (size_t)B * RCH * H;
    ws = (float*)(((uintptr_t)ws + 15) & ~(uintptr_t)15);
    unsigned short* h_bf  = (unsigned short*)ws;
    unsigned short* s_buf = h_bf  + (size_t)N * H;
    unsigned short* mx    = s_buf + (size_t)N * H;
    unsigned short* mn    = mx    + (size_t)N * H;
    unsigned short* Y1bf  = mn    + (size_t)N * H;
    unsigned short* Y2bf  = Y1bf  + (size_t)N * H;
    unsigned short* efs_bf = Y2bf + (size_t)N * H;
    unsigned short* EFW    = efs_bf + (size_t)E * EDGE_DIM;
    short* wf_post_all = (short*)(EFW + (size_t)E * H);
    short* wf_y_all    = wf_post_all + (size_t)L_DEPTH * POST_FRAGS * 8;
    short* wf_ef_all   = wf_y_all + (size_t)L_DEPTH * Y_FRAGS * 8;
    int* deg_i     = (int*)(wf_ef_all + (size_t)L_DEPTH * EF_FRAGS * 8);
    int* row_start = deg_i + N;
    int* cursor    = row_start + N + 1;
    int* es_src    = cursor + N;
    int* es_eid    = es_src + E;
    int* g_start   = es_eid + E;   // B+1 ints

    // input MLP (h fp32 + bf16 shadow)
    k_input_mlp<<<((size_t)N * H + 255) / 256, 256, 0, stream>>>(node_feat, W_in, b_in,
                                                                 h, h_bf, N);

    // edge sort by dst (dst static across layers)
    hipMemsetAsync(deg_i, 0, (size_t)N * sizeof(int), stream);
    k_hist<<<(E + 255) / 256, 256, 0, stream>>>(dst, deg_i, E);
    k_scan<<<1, 1024, 0, stream>>>(deg_i, row_start, cursor, N);
    k_sortscatter<<<(E + 255) / 256, 256, 0, stream>>>(src, dst, cursor, es_src, es_eid, E);
    k_efsort<<<((size_t)E * 4 + 255) / 256, 256, 0, stream>>>(edge_feat, es_eid, efs_bf, E);
    k_scalers<<<(N + 255) / 256, 256, 0, stream>>>(deg_i, invd, amp, att, N);
    k_gbounds<<<(N + 256) / 256, 256, 0, stream>>>(n2g, g_start, N, B);

    // all-layer weight conversion (once)
    {
        int tot = L_DEPTH * (POST_FRAGS + Y_FRAGS + EF_FRAGS);
        k_wconv_all<<<(tot + 255) / 256, 256, 0, stream>>>(pre_W, post_W, wf_y_all,
                                                           wf_post_all, wf_ef_all);
    }

    // layer-0 Y GEMM
    k_ygemm_mfma<<<(N + 63) / 64, 256, 0, stream>>>(h_bf, wf_y_all, Y1bf, Y2bf, N);

    for (int l = 0; l < L_DEPTH; ++l) {
        k_efw<<<(E + 255) / 256, 256, 0, stream>>>(
            efs_bf, wf_ef_all + (size_t)l * EF_FRAGS * 8, EFW, E);
        k_edge_agg<<<N, 256, 0, stream>>>(
            Y1bf, Y2bf, EFW, pre_b + (size_t)l * H,
            es_src, row_start, s_buf, mx, mn, N);
        int doY = (l < L_DEPTH - 1) ? 1 : 0;
        k_post_mfma<<<(N + 31) / 32, 256, 0, stream>>>(
            h, h_bf, s_buf, mx, mn, invd, amp, att,
            wf_post_all + (size_t)l * POST_FRAGS * 8, post_b + (size_t)l * H,
            doY ? (wf_y_all + (size_t)(l + 1) * Y_FRAGS * 8) : wf_y_all,
            Y1bf, Y2bf, doY, N);
    }

    // two-stage readout (no atomics; n2g is sorted) + final MLP
    k_readout_part<<<B * RCH, 256, 0, stream>>>(h, g_start, psum, pmax, B);
    k_readout_final2<<<B, 256, 0, stream>>>(psum, pmax, g_start,
                                            out_W1, out_b1, out_W2, out_b2, out);
}